// Round 13
// baseline (200.590 us; speedup 1.0000x reference)
//
#include <hip/hip_runtime.h>
#include <hip/hip_bf16.h>

typedef __hip_bfloat16 bf16;
typedef unsigned short ushort_t;
typedef __attribute__((ext_vector_type(8))) short short8v;
typedef __attribute__((ext_vector_type(4))) float f32x4;
typedef __attribute__((ext_vector_type(4))) unsigned int uint4v;

// RetNet block: L=2, B=4, S=2048, D=256, H=8, HD=32, FFN*D=1024
#define LYR 2
#define BB 4
#define SS 2048
#define DD 256
#define HH 8
#define HDD 32
#define FFD 1024
#define MM (BB*SS)   // 8192 tokens

__device__ __forceinline__ unsigned int cvtpk(float lo, float hi) {
  unsigned int r;
  asm("v_cvt_pk_bf16_f32 %0, %1, %2" : "=v"(r) : "v"(lo), "v"(hi));
  return r;
}
__device__ __forceinline__ ushort_t f2b1(float x) { return (ushort_t)cvtpk(x, x); }

__device__ __forceinline__ void gload_lds16(const void* g, void* l) {
  __builtin_amdgcn_global_load_lds((const __attribute__((address_space(1))) void*)g,
                                   (__attribute__((address_space(3))) void*)l, 16, 0, 0);
}

// decay exponent: l2g(h) = log2(1 - exp(log(1/32) + h*(log(1/512)-log(1/32))/7))  (negative)
__device__ __forceinline__ float l2g_of(int h) {
  return log2f(1.0f - expf(-3.4657359028f - 0.3960841187f * (float)h));
}

// ---------------- weight transpose+convert + xPos tables (z==14) ----------------
struct WDesc { const float* src; bf16* dst; int K; int N; };
struct WDescA { WDesc d[14]; float* tsn; float* tcs; float* tsc; };
__global__ __launch_bounds__(256) void wconv_k(WDescA da) {
  if (blockIdx.z == 14) {
    int i = (blockIdx.y * 32 + blockIdx.x) * 256 + threadIdx.y * 32 + threadIdx.x;
    if (i >= SS * 16) return;
    int s = i >> 4, j = i & 15;
    float sv = (2.0f * (float)j + 0.4f * (float)HDD) / (1.4f * (float)HDD);
    da.tsc[i] = powf(sv, (float)s * (1.0f / 512.0f));
    float inv_freq = powf(10000.0f, -(float)j * (1.0f / 16.0f));
    float ang = (float)s * inv_freq;
    da.tsn[i] = sinf(ang);
    da.tcs[i] = cosf(ang);
    return;
  }
  WDesc dd = da.d[blockIdx.z];
  int n0 = blockIdx.x * 32, k0 = blockIdx.y * 32;
  if (n0 >= dd.N || k0 >= dd.K) return;
  __shared__ float t[32][33];
  int tx = threadIdx.x, ty = threadIdx.y;   // 32 x 8
  #pragma unroll
  for (int i = 0; i < 32; i += 8) t[ty + i][tx] = dd.src[(size_t)(k0 + ty + i) * dd.N + n0 + tx];
  __syncthreads();
  #pragma unroll
  for (int i = 0; i < 32; i += 8) dd.dst[(size_t)(n0 + ty + i) * dd.K + k0 + tx] = __float2bfloat16(t[tx][ty + i]);
}

// ---------------- LayerNorm over D=256 (one block per row), f32 in, OT out ----------------
template<typename OT>
__global__ __launch_bounds__(256) void ln_k(const float* __restrict__ in, const float* __restrict__ w,
    const float* __restrict__ b, OT* __restrict__ out)
{
  int row = blockIdx.x, t = threadIdx.x;
  float v = in[(size_t)row * DD + t];
  __shared__ float red[4];
  float s = v;
  #pragma unroll
  for (int m = 32; m >= 1; m >>= 1) s += __shfl_xor(s, m);
  if ((t & 63) == 0) red[t >> 6] = s;
  __syncthreads();
  float mu = (red[0] + red[1] + red[2] + red[3]) * (1.0f / 256.0f);
  float d = v - mu;
  float s2 = d * d;
  #pragma unroll
  for (int m = 32; m >= 1; m >>= 1) s2 += __shfl_xor(s2, m);
  __syncthreads();
  if ((t & 63) == 0) red[t >> 6] = s2;
  __syncthreads();
  float var = (red[0] + red[1] + red[2] + red[3]) * (1.0f / 256.0f);
  float o = d * rsqrtf(var + 1e-5f) * w[t] + b[t];
  if constexpr (sizeof(OT) == 2) out[(size_t)row * DD + t] = __float2bfloat16(o);
  else                           out[(size_t)row * DD + t] = o;
}

#define STAGEG(buf, k0s) { \
    _Pragma("unroll") \
    for (int i = 0; i < BM / 32; ++i) { \
      int slot = i * 256 + tid; int row = slot >> 3, blk = slot & 7; \
      gload_lds16(Au + (size_t)(bm + row) * K + (k0s) + ((blk ^ (row & 7))) * 8, &Al[buf][slot * 8]); \
    } \
    _Pragma("unroll") \
    for (int i = 0; i < BN / 32; ++i) { \
      int slot = i * 256 + tid; int row = slot >> 3, blk = slot & 7; \
      gload_lds16(Bu + (size_t)(bn + row) * K + (k0s) + ((blk ^ (row & 7))) * 8, &Bl[buf][slot * 8]); \
    } }

// ---------------- bf16 MFMA GEMM (QKVG projection), double-buffered ----------------
enum { E_QKVG = 0 };

template<int BM, int BN, int K, int EPI>
__global__ __launch_bounds__(256) void mgemm_k(const bf16* __restrict__ Ag, const bf16* __restrict__ Wt,
    void* o0, void* o1, void* o2, void* o3,
    const float* __restrict__ tsn, const float* __restrict__ tcs, const float* __restrict__ tsc)
{
  constexpr int MT = BM / 32, NT = BN / 32;
  constexpr int WMH = BM / 2, WNH = BN / 2;
  __shared__ __align__(16) ushort_t Al[2][BM * 64];
  __shared__ __align__(16) ushort_t Bl[2][BN * 64];
  const int bm = blockIdx.x * BM;
  const int bn = blockIdx.y * BN;
  const int tid = threadIdx.x;
  const int lane = tid & 63, w = tid >> 6;
  const int lg = lane >> 4, ln = lane & 15;
  const int wr = w >> 1, wc = w & 1;
  const ushort_t* Au = (const ushort_t*)Ag;
  const ushort_t* Bu = (const ushort_t*)Wt;
  f32x4 acc[MT][NT] = {};

  STAGEG(0, 0)
  asm volatile("s_waitcnt vmcnt(0)" ::: "memory");
  __builtin_amdgcn_s_barrier();

  int cur = 0;
  for (int k0 = 0; k0 < K; k0 += 64) {
    if (k0 + 64 < K) STAGEG(cur ^ 1, k0 + 64)
    #pragma unroll
    for (int kh = 0; kh < 2; ++kh) {
      short8v af[MT], bfr[NT];
      #pragma unroll
      for (int mt = 0; mt < MT; ++mt) {
        int row = wr * WMH + mt * 16 + ln;
        af[mt] = *(const short8v*)&Al[cur][row * 64 + (((kh * 4 + lg) ^ (row & 7))) * 8];
      }
      #pragma unroll
      for (int nt = 0; nt < NT; ++nt) {
        int row = wc * WNH + nt * 16 + ln;
        bfr[nt] = *(const short8v*)&Bl[cur][row * 64 + (((kh * 4 + lg) ^ (row & 7))) * 8];
      }
      #pragma unroll
      for (int mt = 0; mt < MT; ++mt)
        #pragma unroll
        for (int nt = 0; nt < NT; ++nt)
          acc[mt][nt] = __builtin_amdgcn_mfma_f32_16x16x32_bf16(af[mt], bfr[nt], acc[mt][nt], 0, 0, 0);
    }
    asm volatile("s_waitcnt vmcnt(0)" ::: "memory");
    __builtin_amdgcn_s_barrier();
    cur ^= 1;
  }

  #pragma unroll
  for (int mt = 0; mt < MT; ++mt)
    #pragma unroll
    for (int nt = 0; nt < NT; ++nt) {
      const int colbase = bn + wc * WNH + nt * 16;
      const int sec = colbase >> 8;          // 0=Q 1=K 2=V 3=G (uniform per block)
      const int c = (colbase & 255) + ln;
      const int grow0 = bm + wr * WMH + mt * 16 + lg * 4;
      if (sec <= 1) {
        const int jj = (c & 31) >> 1;
        const float l2g = l2g_of(c >> 5);
        #pragma unroll
        for (int r = 0; r < 4; ++r) {
          const int grow = grow0 + r;
          const int s = grow & (SS - 1);
          float v = acc[mt][nt][r];
          float pv = __shfl_xor(v, 1);
          float scv = tsc[s * 16 + jj];
          if (sec == 1) scv = 1.0f / scv;
          float ce = tcs[s * 16 + jj] * scv, se = tsn[s * 16 + jj] * scv;
          float o = (ln & 1) ? (v * ce + pv * se) : (v * ce - pv * se);
          if (sec == 0) o *= exp2f(l2g * (float)s);   // fold decay g^n into Q
          bf16* dst = (sec == 0) ? (bf16*)o0 : (bf16*)o1;
          dst[(size_t)grow * DD + c] = __float2bfloat16(o);
        }
      } else if (sec == 2) {
        // V transposed + fold g^(-m): vT[(b*8+h)*32 + d][s] = v(m=s,d) * g^(-s)
        const int b = grow0 >> 11, s0 = grow0 & (SS - 1);
        const int h = c >> 5, d = c & 31;
        const float nl2g = -l2g_of(h);                // positive
        float v0 = acc[mt][nt][0] * exp2f(nl2g * (float)(s0 + 0));
        float v1 = acc[mt][nt][1] * exp2f(nl2g * (float)(s0 + 1));
        float v2 = acc[mt][nt][2] * exp2f(nl2g * (float)(s0 + 2));
        float v3 = acc[mt][nt][3] * exp2f(nl2g * (float)(s0 + 3));
        uint2 pk;
        pk.x = cvtpk(v0, v1);
        pk.y = cvtpk(v2, v3);
        *(uint2*)((ushort_t*)o2 + ((size_t)(b * 8 + h) * 32 + d) * SS + s0) = pk;
      } else {
        #pragma unroll
        for (int r = 0; r < 4; ++r)
          ((float*)o3)[(size_t)(grow0 + r) * DD + c] = acc[mt][nt][r];
      }
    }
}

// ---------------- FFN mega-kernel: Wo+res+LN2 -> FFN1+GELU -> FFN2+b+res -> LNf (-> LN1') ----------------
// BM=16 rows/block, grid MM/16=512, 4 waves; wave w owns cols [w*64, w*64+64).
// LDS exactly 80KB: Bs 64K dbuf, AX 8K (Wo-A dbuf then Xs), Us 8K (LN red + GELU chunk).
template<bool LAST>
__global__ __launch_bounds__(256) void ffn_mega(
    const bf16* __restrict__ ubg, const bf16* __restrict__ wotg,
    const bf16* __restrict__ w1tg, const bf16* __restrict__ w2tg,
    const float* __restrict__ b1v, const float* __restrict__ b2v,
    const float* __restrict__ resin,
    float* __restrict__ yres, bf16* __restrict__ xn, float* __restrict__ dout,
    const float* __restrict__ l2w, const float* __restrict__ l2b,
    const float* __restrict__ lfw, const float* __restrict__ lfb,
    const float* __restrict__ l1w, const float* __restrict__ l1b)
{
  __shared__ __align__(16) ushort_t Bs[2][256 * 64];   // 64 KB
  __shared__ __align__(16) ushort_t AX[4096];          // 8 KB: Wo-A dbuf (2x1024) then Xs[16][256]
  __shared__ __align__(16) ushort_t Us[4096];          // 8 KB: LN red scratch + GELU chunk [16][256]

  const int bm = blockIdx.x * 16;
  const int tid = threadIdx.x;
  const int lane = tid & 63, w = tid >> 6;
  const int lg = lane >> 4, ln = lane & 15;
  const int row0 = lg * 4;
  const ushort_t* ubu  = (const ushort_t*)ubg;
  const ushort_t* wotu = (const ushort_t*)wotg;
  const ushort_t* w1tu = (const ushort_t*)w1tg;
  const ushort_t* w2tu = (const ushort_t*)w2tg;
  float* red = (float*)Us;   // [4 waves][16 rows][2], 512 B

  // early residual prefetch (consumed after Wo phase)
  float resv[4][4];
  #pragma unroll
  for (int nt = 0; nt < 4; ++nt) {
    const int gcol = w * 64 + nt * 16 + ln;
    #pragma unroll
    for (int r = 0; r < 4; ++r)
      resv[nt][r] = resin[(size_t)(bm + row0 + r) * DD + gcol];
  }

  #define STAGEB(buf, base, stride, koff) { \
    _Pragma("unroll") \
    for (int i = 0; i < 8; ++i) { \
      int slot = i * 256 + tid; int row = slot >> 3, blk = slot & 7; \
      gload_lds16((base) + (size_t)row * (stride) + (koff) + ((blk ^ (row & 7))) * 8, &Bs[buf][slot * 8]); \
    } }
  #define STAGEA(buf, koff) { \
    if (tid < 128) { int row = tid >> 3, blk = tid & 7; \
      gload_lds16(ubu + (size_t)(bm + row) * DD + (koff) + ((blk ^ (row & 7))) * 8, &AX[(buf) * 1024 + tid * 8]); } }
  #define DRAIN asm volatile("s_waitcnt vmcnt(0)" ::: "memory"); __builtin_amdgcn_s_barrier();

  STAGEA(0, 0)
  STAGEB(0, wotu, 256, 0)
  DRAIN
  int cur = 0;

  // ---- phase 1: Wo GEMM (K=256, 4 steps) ----
  f32x4 accw[4] = {};
  #pragma unroll
  for (int s = 0; s < 4; ++s) {
    if (s < 3) { STAGEA(cur ^ 1, (s + 1) * 64) STAGEB(cur ^ 1, wotu, 256, (s + 1) * 64) }
    else       { STAGEB(cur ^ 1, w1tu, 256, 0) }
    #pragma unroll
    for (int kh = 0; kh < 2; ++kh) {
      short8v af = *(const short8v*)&AX[cur * 1024 + ln * 64 + (((kh * 4 + lg) ^ (ln & 7))) * 8];
      #pragma unroll
      for (int nt = 0; nt < 4; ++nt) {
        int row = w * 64 + nt * 16 + ln;
        short8v bf_ = *(const short8v*)&Bs[cur][row * 64 + (((kh * 4 + lg) ^ (row & 7))) * 8];
        accw[nt] = __builtin_amdgcn_mfma_f32_16x16x32_bf16(af, bf_, accw[nt], 0, 0, 0);
      }
    }
    DRAIN
    cur ^= 1;
  }

  // ---- v = Wo + residual; LN2; write Xs (bf16, swizzled A-layout) ----
  float v[4][4];
  #pragma unroll
  for (int nt = 0; nt < 4; ++nt)
    #pragma unroll
    for (int r = 0; r < 4; ++r) v[nt][r] = accw[nt][r] + resv[nt][r];
  float mu[4], rsg[4];
  {
    #pragma unroll
    for (int r = 0; r < 4; ++r) {
      float s1 = 0.f, s2 = 0.f;
      #pragma unroll
      for (int nt = 0; nt < 4; ++nt) { s1 += v[nt][r]; s2 += v[nt][r] * v[nt][r]; }
      #pragma unroll
      for (int m = 8; m >= 1; m >>= 1) { s1 += __shfl_xor(s1, m); s2 += __shfl_xor(s2, m); }
      if (ln == 0) { red[(w * 16 + row0 + r) * 2] = s1; red[(w * 16 + row0 + r) * 2 + 1] = s2; }
    }
    __syncthreads();
    #pragma unroll
    for (int r = 0; r < 4; ++r) {
      float S = 0.f, S2 = 0.f;
      #pragma unroll
      for (int ww = 0; ww < 4; ++ww) { S += red[(ww * 16 + row0 + r) * 2]; S2 += red[(ww * 16 + row0 + r) * 2 + 1]; }
      float m_ = S * (1.0f / 256.0f);
      mu[r] = m_; rsg[r] = rsqrtf(S2 * (1.0f / 256.0f) - m_ * m_ + 1e-5f);
    }
  }
  __syncthreads();   // red (Us area) reads done before any later Us writes
  #pragma unroll
  for (int nt = 0; nt < 4; ++nt) {
    const int gcol = w * 64 + nt * 16 + ln;
    const float lwv = l2w[gcol], lbv = l2b[gcol];
    const int off = nt * 16 + ln, blk = off >> 3, sub = off & 7;
    #pragma unroll
    for (int r = 0; r < 4; ++r) {
      const int row = row0 + r;
      float xv = (v[nt][r] - mu[r]) * rsg[r] * lwv + lbv;
      AX[row * 256 + w * 64 + ((blk ^ (row & 7)) << 3) + sub] = f2b1(xv);
    }
  }
  __syncthreads();

  // ---- phases 2..9: 4 chunks of {FFN1 (K=256) -> GELU -> FFN2 partial (K-slice 256)} ----
  f32x4 acc2[4] = {};
  #pragma unroll
  for (int c = 0; c < 4; ++c) {
    f32x4 acc1[4] = {};
    #pragma unroll
    for (int s = 0; s < 4; ++s) {
      if (s < 3) { STAGEB(cur ^ 1, w1tu + (size_t)c * 65536, 256, (s + 1) * 64) }
      else       { STAGEB(cur ^ 1, w2tu + c * 256, 1024, 0) }
      #pragma unroll
      for (int kh = 0; kh < 2; ++kh) {
        short8v af = *(const short8v*)&AX[ln * 256 + s * 64 + (((kh * 4 + lg) ^ (ln & 7))) * 8];
        #pragma unroll
        for (int nt = 0; nt < 4; ++nt) {
          int row = w * 64 + nt * 16 + ln;
          short8v bf_ = *(const short8v*)&Bs[cur][row * 64 + (((kh * 4 + lg) ^ (row & 7))) * 8];
          acc1[nt] = __builtin_amdgcn_mfma_f32_16x16x32_bf16(af, bf_, acc1[nt], 0, 0, 0);
        }
      }
      DRAIN
      cur ^= 1;
    }
    // GELU -> Us (bf16, swizzled A-layout)
    #pragma unroll
    for (int nt = 0; nt < 4; ++nt) {
      const int gcol1 = c * 256 + w * 64 + nt * 16 + ln;
      const float bb = b1v[gcol1];
      const int off = nt * 16 + ln, blk = off >> 3, sub = off & 7;
      #pragma unroll
      for (int r = 0; r < 4; ++r) {
        const int row = row0 + r;
        float t = acc1[nt][r] + bb;
        t = 0.5f * t * (1.0f + erff(t * 0.70710678118654752f));
        Us[row * 256 + w * 64 + ((blk ^ (row & 7)) << 3) + sub] = f2b1(t);
      }
    }
    __syncthreads();
    #pragma unroll
    for (int s = 0; s < 4; ++s) {
      if (s < 3)      { STAGEB(cur ^ 1, w2tu + c * 256, 1024, (s + 1) * 64) }
      else if (c < 3) { STAGEB(cur ^ 1, w1tu + (size_t)(c + 1) * 65536, 256, 0) }
      #pragma unroll
      for (int kh = 0; kh < 2; ++kh) {
        short8v af = *(const short8v*)&Us[ln * 256 + s * 64 + (((kh * 4 + lg) ^ (ln & 7))) * 8];
        #pragma unroll
        for (int nt = 0; nt < 4; ++nt) {
          int row = w * 64 + nt * 16 + ln;
          short8v bf_ = *(const short8v*)&Bs[cur][row * 64 + (((kh * 4 + lg) ^ (row & 7))) * 8];
          acc2[nt] = __builtin_amdgcn_mfma_f32_16x16x32_bf16(af, bf_, acc2[nt], 0, 0, 0);
        }
      }
      DRAIN
      cur ^= 1;
    }
  }

  // ---- epilogue: f = FFN2 + b2 + v; LNf; (LAST: dout) else (yres, LN1' -> xn) ----
  float f[4][4];
  #pragma unroll
  for (int nt = 0; nt < 4; ++nt) {
    const int gcol = w * 64 + nt * 16 + ln;
    const float bb = b2v[gcol];
    #pragma unroll
    for (int r = 0; r < 4; ++r) f[nt][r] = acc2[nt][r] + bb + v[nt][r];
  }
  {
    #pragma unroll
    for (int r = 0; r < 4; ++r) {
      float s1 = 0.f, s2 = 0.f;
      #pragma unroll
      for (int nt = 0; nt < 4; ++nt) { s1 += f[nt][r]; s2 += f[nt][r] * f[nt][r]; }
      #pragma unroll
      for (int m = 8; m >= 1; m >>= 1) { s1 += __shfl_xor(s1, m); s2 += __shfl_xor(s2, m); }
      if (ln == 0) { red[(w * 16 + row0 + r) * 2] = s1; red[(w * 16 + row0 + r) * 2 + 1] = s2; }
    }
    __syncthreads();
    #pragma unroll
    for (int r = 0; r < 4; ++r) {
      float S = 0.f, S2 = 0.f;
      #pragma unroll
      for (int ww = 0; ww < 4; ++ww) { S += red[(ww * 16 + row0 + r) * 2]; S2 += red[(ww * 16 + row0 + r) * 2 + 1]; }
      float m_ = S * (1.0f / 256.0f);
      mu[r] = m_; rsg[r] = rsqrtf(S2 * (1.0f / 256.0f) - m_ * m_ + 1e-5f);
    }
  }
  float u[4][4];
  #pragma unroll
  for (int nt = 0; nt < 4; ++nt) {
    const int gcol = w * 64 + nt * 16 + ln;
    const float lwv = lfw[gcol], lbv = lfb[gcol];
    #pragma unroll
    for (int r = 0; r < 4; ++r)
      u[nt][r] = (f[nt][r] - mu[r]) * rsg[r] * lwv + lbv;
  }
  if constexpr (LAST) {
    #pragma unroll
    for (int nt = 0; nt < 4; ++nt) {
      const int gcol = w * 64 + nt * 16 + ln;
      #pragma unroll
      for (int r = 0; r < 4; ++r)
        dout[(size_t)(bm + row0 + r) * DD + gcol] = u[nt][r];
    }
  } else {
    __syncthreads();
    #pragma unroll
    for (int r = 0; r < 4; ++r) {
      float s1 = 0.f, s2 = 0.f;
      #pragma unroll
      for (int nt = 0; nt < 4; ++nt) { s1 += u[nt][r]; s2 += u[nt][r] * u[nt][r]; }
      #pragma unroll
      for (int m = 8; m >= 1; m >>= 1) { s1 += __shfl_xor(s1, m); s2 += __shfl_xor(s2, m); }
      if (ln == 0) { red[(w * 16 + row0 + r) * 2] = s1; red[(w * 16 + row0 + r) * 2 + 1] = s2; }
    }
    __syncthreads();
    float mu2[4], rs2[4];
    #pragma unroll
    for (int r = 0; r < 4; ++r) {
      float S = 0.f, S2 = 0.f;
      #pragma unroll
      for (int ww = 0; ww < 4; ++ww) { S += red[(ww * 16 + row0 + r) * 2]; S2 += red[(ww * 16 + row0 + r) * 2 + 1]; }
      float m_ = S * (1.0f / 256.0f);
      mu2[r] = m_; rs2[r] = rsqrtf(S2 * (1.0f / 256.0f) - m_ * m_ + 1e-5f);
    }
    #pragma unroll
    for (int nt = 0; nt < 4; ++nt) {
      const int gcol = w * 64 + nt * 16 + ln;
      const float lwv = l1w[gcol], lbv = l1b[gcol];
      #pragma unroll
      for (int r = 0; r < 4; ++r) {
        const size_t idx = (size_t)(bm + row0 + r) * DD + gcol;
        yres[idx] = u[nt][r];
        xn[idx] = __float2bfloat16((u[nt][r] - mu2[r]) * rs2[r] * lwv + lbv);
      }
    }
  }
  #undef STAGEB
  #undef STAGEA
  #undef DRAIN
}

// ---------------- Retention + fused GroupNorm/SiLU-gate ----------------
// Decay pre-folded: q *= g^n, vT *= g^(-m). Inner loop: raw QK -> pack -> PV.
__global__ __launch_bounds__(256) void attn_k(const bf16* __restrict__ qg, const bf16* __restrict__ kg,
    const bf16* __restrict__ vtg, const float* __restrict__ gbuf,
    const float* __restrict__ gnw, const float* __restrict__ gnb, bf16* __restrict__ ub)
{
  __shared__ __align__(16) ushort_t Kl[2][64 * 32];      // [m][k], blk ^= m&3
  __shared__ __align__(16) ushort_t Vl[2][32 * 64];      // [d][m], blk ^= d&7
  __shared__ __align__(16) unsigned int Pl[4][512];      // per wave: P^T[n=ln][64 m] bf16

  const int bh = blockIdx.x;
  const int b = bh >> 3, h = bh & (HH - 1);
  const int n0 = ((int)gridDim.y - 1 - (int)blockIdx.y) * 64;
  const int tid = threadIdx.x;
  const int w = tid >> 6, lane = tid & 63;
  const int lg = lane >> 4, ln = lane & 15;

  const size_t base = (size_t)b * SS * DD + h * HDD;
  const ushort_t* qp = (const ushort_t*)qg + base;
  const ushort_t* kp = (const ushort_t*)kg + base;
  const ushort_t* vtp = (const ushort_t*)vtg + (size_t)(b * 8 + h) * 32 * SS;

  const int n = n0 + w * 16 + ln;
  const short8v qf = *(const short8v*)(qp + (size_t)n * DD + lg * 8);

  const float l2g = l2g_of(h);                     // negative; only for window calc
  f32x4 acc0 = {0,0,0,0}, acc1 = {0,0,0,0};

  const int Wwin = (int)(20.0f / (-l2g)) + 1;
  int m_lo = 0;
  if (n0 > Wwin) m_lo = ((n0 - Wwin) >> 6) << 6;

  const int Krow = tid >> 2, Kc8 = tid & 3;
  const int Vrow = tid >> 3, Vc8 = tid & 7;

  #define STAGE(buf, m0s) { \
    gload_lds16(kp + (size_t)((m0s) + Krow) * DD + ((Kc8 ^ (Krow & 3)) * 8), &Kl[buf][tid * 8]); \
    gload_lds16(vtp + (size_t)Vrow * SS + (m0s) + ((Vc8 ^ (Vrow & 7)) * 8), &Vl[buf][tid * 8]); }

  STAGE(0, m_lo)
  asm volatile("s_waitcnt vmcnt(0)" ::: "memory");
  __builtin_amdgcn_s_barrier();

  int cur = 0;
  for (int m0 = m_lo; m0 <= n0; m0 += 64) {
    if (m0 < n0) STAGE(cur ^ 1, m0 + 64)
    const bool diag = (m0 == n0);
    __builtin_amdgcn_s_setprio(1);
    #pragma unroll
    for (int mt = 0; mt < 4; ++mt) {
      const int krow = mt * 16 + ln;
      short8v kf = *(const short8v*)&Kl[cur][krow * 32 + ((lg ^ (krow & 3)) << 3)];
      f32x4 z = {0,0,0,0};
      f32x4 pa = __builtin_amdgcn_mfma_f32_16x16x32_bf16(kf, qf, z, 0, 0, 0);
      float v0 = pa[0], v1 = pa[1], v2 = pa[2], v3 = pa[3];
      if (diag) {
        const int m = n0 + mt * 16 + lg * 4;
        v0 = (n < m)     ? 0.f : v0;
        v1 = (n < m + 1) ? 0.f : v1;
        v2 = (n < m + 2) ? 0.f : v2;
        v3 = (n < m + 3) ? 0.f : v3;
      }
      uint2 pk;
      pk.x = cvtpk(v0, v1);
      pk.y = cvtpk(v2, v3);
      const int blk = (mt * 2 + (lg >> 1)) ^ (ln & 7);
      *(uint2*)&Pl[w][ln * 32 + blk * 4 + (lg & 1) * 2] = pk;
    }
    #pragma unroll
    for (int hh = 0; hh < 2; ++hh) {
      const int pblk = (hh * 4 + lg) ^ (ln & 7);
      uint4v pw = *(const uint4v*)&Pl[w][ln * 32 + pblk * 4];
      short8v pf = __builtin_bit_cast(short8v, pw);
      #pragma unroll
      for (int dt = 0; dt < 2; ++dt) {
        const int d = dt * 16 + ln;
        short8v vf = *(const short8v*)&Vl[cur][d * 64 + (((hh * 4 + lg) ^ (d & 7)) << 3)];
        if (dt == 0) acc0 = __builtin_amdgcn_mfma_f32_16x16x32_bf16(vf, pf, acc0, 0, 0, 0);
        else         acc1 = __builtin_amdgcn_mfma_f32_16x16x32_bf16(vf, pf, acc1, 0, 0, 0);
      }
    }
    __builtin_amdgcn_s_setprio(0);
    asm volatile("s_waitcnt vmcnt(0)" ::: "memory");
    __builtin_amdgcn_s_barrier();
    cur ^= 1;
  }
  #undef STAGE

  // ---- fused GroupNorm (per head) + SiLU gate ----
  float gwv[8], gbv[8];
  #pragma unroll
  for (int dt = 0; dt < 2; ++dt) {
    f32x4 a = *(const f32x4*)&gnw[h * 32 + dt * 16 + lg * 4];
    f32x4 c = *(const f32x4*)&gnb[h * 32 + dt * 16 + lg * 4];
    #pragma unroll
    for (int r = 0; r < 4; ++r) { gwv[dt * 4 + r] = a[r]; gbv[dt * 4 + r] = c[r]; }
  }
  float s = 0.f;
  #pragma unroll
  for (int r = 0; r < 4; ++r) s += acc0[r] + acc1[r];
  s += __shfl_xor(s, 16); s += __shfl_xor(s, 32);
  const float mu = s * (1.0f / 32.0f);
  float s2 = 0.f;
  #pragma unroll
  for (int r = 0; r < 4; ++r) { float d0 = acc0[r] - mu, d1 = acc1[r] - mu; s2 += d0 * d0 + d1 * d1; }
  s2 += __shfl_xor(s2, 16); s2 += __shfl_xor(s2, 32);
  const float rs = rsqrtf(s2 * (1.0f / 32.0f) + 1e-5f);
  const size_t rowoff = ((size_t)b * SS + n) * DD + h * 32;
  #pragma unroll
  for (int dt = 0; dt < 2; ++dt) {
    f32x4 yv = dt ? acc1 : acc0;
    f32x4 gv = *(const f32x4*)&gbuf[rowoff + dt * 16 + lg * 4];
    float o0, o1, o2, o3;
    {
      float yn0 = (yv[0] - mu) * rs * gwv[dt * 4 + 0] + gbv[dt * 4 + 0];
      float yn1 = (yv[1] - mu) * rs * gwv[dt * 4 + 1] + gbv[dt * 4 + 1];
      float yn2 = (yv[2] - mu) * rs * gwv[dt * 4 + 2] + gbv[dt * 4 + 2];
      float yn3 = (yv[3] - mu) * rs * gwv[dt * 4 + 3] + gbv[dt * 4 + 3];
      o0 = gv[0] / (1.0f + expf(-gv[0])) * yn0;
      o1 = gv[1] / (1.0f + expf(-gv[1])) * yn1;
      o2 = gv[2] / (1.0f + expf(-gv[2])) * yn2;
      o3 = gv[3] / (1.0f + expf(-gv[3])) * yn3;
    }
    uint2 pk;
    pk.x = cvtpk(o0, o1);
    pk.y = cvtpk(o2, o3);
    *(uint2*)((ushort_t*)ub + rowoff + dt * 16 + lg * 4) = pk;
  }
}

extern "C" void kernel_launch(void* const* d_in, const int* in_sizes, int n_in,
                              void* d_out, int out_size, void* d_ws, size_t ws_size,
                              hipStream_t stream)
{
  const float* X    = (const float*)d_in[0];
  const float* Wq   = (const float*)d_in[1];
  const float* Wk   = (const float*)d_in[2];
  const float* Wv   = (const float*)d_in[3];
  const float* Wg   = (const float*)d_in[4];
  const float* Wo   = (const float*)d_in[5];
  const float* gnw  = (const float*)d_in[6];
  const float* gnb  = (const float*)d_in[7];
  const float* ln1w = (const float*)d_in[8];
  const float* ln1b = (const float*)d_in[9];
  const float* ln2w = (const float*)d_in[10];
  const float* ln2b = (const float*)d_in[11];
  const float* w1   = (const float*)d_in[12];
  const float* b1   = (const float*)d_in[13];
  const float* w2   = (const float*)d_in[14];
  const float* b2   = (const float*)d_in[15];
  const float* lnfw = (const float*)d_in[16];
  const float* lnfb = (const float*)d_in[17];

  // Workspace (~40 MiB)
  char* p = (char*)d_ws;
  const size_t AF  = (size_t)MM * DD * sizeof(float);  // 8 MiB
  const size_t ABF = (size_t)MM * DD * sizeof(bf16);   // 4 MiB
  bf16*  xn   = (bf16*)p;  p += ABF;
  bf16*  qb   = (bf16*)p;  p += ABF;
  bf16*  kb   = (bf16*)p;  p += ABF;
  bf16*  vT   = (bf16*)p;  p += ABF;   // [B][H][32][S], pre-scaled by g^(-m)
  bf16*  ub   = (bf16*)p;  p += ABF;
  float* gbuf = (float*)p; p += AF;
  float* yres = (float*)p; p += AF;
  bf16*  wqkvgt = (bf16*)p; p += (size_t)2 * 1024 * 256 * sizeof(bf16);
  bf16*  wot    = (bf16*)p; p += (size_t)2 * 256 * 256 * sizeof(bf16);
  bf16*  w1t    = (bf16*)p; p += (size_t)2 * 1024 * 256 * sizeof(bf16);
  bf16*  w2t    = (bf16*)p; p += (size_t)2 * 256 * 1024 * sizeof(bf16);
  float* tsn  = (float*)p; p += SS * 16 * sizeof(float);
  float* tcs  = (float*)p; p += SS * 16 * sizeof(float);
  float* tsc  = (float*)p; p += SS * 16 * sizeof(float);

  {
    WDescA da;
    for (int l = 0; l < 2; ++l) {
      da.d[l * 7 + 0] = { Wq + (size_t)l * 65536, wqkvgt + (size_t)l * 262144 + 0 * 65536, 256, 256 };
      da.d[l * 7 + 1] = { Wk + (size_t)l * 65536, wqkvgt + (size_t)l * 262144 + 1 * 65536, 256, 256 };
      da.d[l * 7 + 2] = { Wv + (size_t)l * 65536, wqkvgt + (size_t)l * 262144 + 2 * 65536, 256, 256 };
      da.d[l * 7 + 3] = { Wg + (size_t)l * 65536, wqkvgt + (size_t)l * 262144 + 3 * 65536, 256, 256 };
      da.d[l * 7 + 4] = { Wo + (size_t)l * 65536, wot + (size_t)l * 65536, 256, 256 };
      da.d[l * 7 + 5] = { w1 + (size_t)l * 262144, w1t + (size_t)l * 262144, 256, 1024 };
      da.d[l * 7 + 6] = { w2 + (size_t)l * 262144, w2t + (size_t)l * 262144, 1024, 256 };
    }
    da.tsn = tsn; da.tcs = tcs; da.tsc = tsc;
    wconv_k<<<dim3(32, 32, 15), dim3(32, 8), 0, stream>>>(da);
  }

  // layer 0 LN1 (layer 1's LN1 is fused into layer 0's mega epilogue)
  ln_k<bf16><<<dim3(MM), 256, 0, stream>>>(X, ln1w, ln1b, xn);

  for (int l = 0; l < LYR; ++l) {
    mgemm_k<64, 128, DD, E_QKVG><<<dim3(MM / 64, 1024 / 128), 256, 0, stream>>>(
        xn, wqkvgt + (size_t)l * 262144, qb, kb, vT, gbuf, tsn, tcs, tsc);
    attn_k<<<dim3(BB * HH, SS / 64), 256, 0, stream>>>(qb, kb, vT, gbuf, gnw + l * DD, gnb + l * DD, ub);
    if (l == LYR - 1) {
      ffn_mega<true><<<dim3(MM / 16), 256, 0, stream>>>(
          ub, wot + (size_t)l * 65536, w1t + (size_t)l * 262144, w2t + (size_t)l * 262144,
          b1 + l * FFD, b2 + l * DD, (l == 0) ? X : yres,
          nullptr, nullptr, (float*)d_out,
          ln2w + l * DD, ln2b + l * DD, lnfw, lnfb, nullptr, nullptr);
    } else {
      ffn_mega<false><<<dim3(MM / 16), 256, 0, stream>>>(
          ub, wot + (size_t)l * 65536, w1t + (size_t)l * 262144, w2t + (size_t)l * 262144,
          b1 + l * FFD, b2 + l * DD, (l == 0) ? X : yres,
          yres, xn, nullptr,
          ln2w + l * DD, ln2b + l * DD, lnfw, lnfb, ln1w + (l + 1) * DD, ln1b + (l + 1) * DD);
    }
  }
}

// Round 14
// 191.971 us; speedup vs baseline: 1.0449x; 1.0449x over previous
//
#include <hip/hip_runtime.h>
#include <hip/hip_bf16.h>

typedef __hip_bfloat16 bf16;
typedef unsigned short ushort_t;
typedef __attribute__((ext_vector_type(8))) short short8v;
typedef __attribute__((ext_vector_type(4))) float f32x4;
typedef __attribute__((ext_vector_type(4))) unsigned int uint4v;

// RetNet block: L=2, B=4, S=2048, D=256, H=8, HD=32, FFN*D=1024
#define LYR 2
#define BB 4
#define SS 2048
#define DD 256
#define HH 8
#define HDD 32
#define FFD 1024
#define MM (BB*SS)   // 8192 tokens

__device__ __forceinline__ unsigned int cvtpk(float lo, float hi) {
  unsigned int r;
  asm("v_cvt_pk_bf16_f32 %0, %1, %2" : "=v"(r) : "v"(lo), "v"(hi));
  return r;
}
__device__ __forceinline__ ushort_t f2b1(float x) { return (ushort_t)cvtpk(x, x); }

__device__ __forceinline__ void gload_lds16(const void* g, void* l) {
  __builtin_amdgcn_global_load_lds((const __attribute__((address_space(1))) void*)g,
                                   (__attribute__((address_space(3))) void*)l, 16, 0, 0);
}

// decay exponent: l2g(h) = log2(1 - exp(log(1/32) + h*(log(1/512)-log(1/32))/7))  (negative)
__device__ __forceinline__ float l2g_of(int h) {
  return log2f(1.0f - expf(-3.4657359028f - 0.3960841187f * (float)h));
}

// ---------------- weight transpose+convert + xPos tables (z==14) ----------------
struct WDesc { const float* src; bf16* dst; int K; int N; };
struct WDescA { WDesc d[14]; float* tsn; float* tcs; float* tsc; };
__global__ __launch_bounds__(256) void wconv_k(WDescA da) {
  if (blockIdx.z == 14) {
    int i = (blockIdx.y * 32 + blockIdx.x) * 256 + threadIdx.y * 32 + threadIdx.x;
    if (i >= SS * 16) return;
    int s = i >> 4, j = i & 15;
    float sv = (2.0f * (float)j + 0.4f * (float)HDD) / (1.4f * (float)HDD);
    da.tsc[i] = powf(sv, (float)s * (1.0f / 512.0f));
    float inv_freq = powf(10000.0f, -(float)j * (1.0f / 16.0f));
    float ang = (float)s * inv_freq;
    da.tsn[i] = sinf(ang);
    da.tcs[i] = cosf(ang);
    return;
  }
  WDesc dd = da.d[blockIdx.z];
  int n0 = blockIdx.x * 32, k0 = blockIdx.y * 32;
  if (n0 >= dd.N || k0 >= dd.K) return;
  __shared__ float t[32][33];
  int tx = threadIdx.x, ty = threadIdx.y;   // 32 x 8
  #pragma unroll
  for (int i = 0; i < 32; i += 8) t[ty + i][tx] = dd.src[(size_t)(k0 + ty + i) * dd.N + n0 + tx];
  __syncthreads();
  #pragma unroll
  for (int i = 0; i < 32; i += 8) dd.dst[(size_t)(n0 + ty + i) * dd.K + k0 + tx] = __float2bfloat16(t[tx][ty + i]);
}

// ---------------- LayerNorm over D=256 (one block per row), f32 in, OT out ----------------
template<typename OT>
__global__ __launch_bounds__(256) void ln_k(const float* __restrict__ in, const float* __restrict__ w,
    const float* __restrict__ b, OT* __restrict__ out)
{
  int row = blockIdx.x, t = threadIdx.x;
  float v = in[(size_t)row * DD + t];
  __shared__ float red[4];
  float s = v;
  #pragma unroll
  for (int m = 32; m >= 1; m >>= 1) s += __shfl_xor(s, m);
  if ((t & 63) == 0) red[t >> 6] = s;
  __syncthreads();
  float mu = (red[0] + red[1] + red[2] + red[3]) * (1.0f / 256.0f);
  float d = v - mu;
  float s2 = d * d;
  #pragma unroll
  for (int m = 32; m >= 1; m >>= 1) s2 += __shfl_xor(s2, m);
  __syncthreads();
  if ((t & 63) == 0) red[t >> 6] = s2;
  __syncthreads();
  float var = (red[0] + red[1] + red[2] + red[3]) * (1.0f / 256.0f);
  float o = d * rsqrtf(var + 1e-5f) * w[t] + b[t];
  if constexpr (sizeof(OT) == 2) out[(size_t)row * DD + t] = __float2bfloat16(o);
  else                           out[(size_t)row * DD + t] = o;
}

#define STAGEG(buf, k0s) { \
    _Pragma("unroll") \
    for (int i = 0; i < BM / 32; ++i) { \
      int slot = i * 256 + tid; int row = slot >> 3, blk = slot & 7; \
      gload_lds16(Au + (size_t)(bm + row) * K + (k0s) + ((blk ^ (row & 7))) * 8, &Al[buf][slot * 8]); \
    } \
    _Pragma("unroll") \
    for (int i = 0; i < BN / 32; ++i) { \
      int slot = i * 256 + tid; int row = slot >> 3, blk = slot & 7; \
      gload_lds16(Bu + (size_t)(bn + row) * K + (k0s) + ((blk ^ (row & 7))) * 8, &Bl[buf][slot * 8]); \
    } }

// ---------------- bf16 MFMA GEMM (QKVG projection), double-buffered ----------------
enum { E_QKVG = 0 };

template<int BM, int BN, int K, int EPI>
__global__ __launch_bounds__(256) void mgemm_k(const bf16* __restrict__ Ag, const bf16* __restrict__ Wt,
    void* o0, void* o1, void* o2, void* o3,
    const float* __restrict__ tsn, const float* __restrict__ tcs, const float* __restrict__ tsc)
{
  constexpr int MT = BM / 32, NT = BN / 32;
  constexpr int WMH = BM / 2, WNH = BN / 2;
  __shared__ __align__(16) ushort_t Al[2][BM * 64];
  __shared__ __align__(16) ushort_t Bl[2][BN * 64];
  const int bm = blockIdx.x * BM;
  const int bn = blockIdx.y * BN;
  const int tid = threadIdx.x;
  const int lane = tid & 63, w = tid >> 6;
  const int lg = lane >> 4, ln = lane & 15;
  const int wr = w >> 1, wc = w & 1;
  const ushort_t* Au = (const ushort_t*)Ag;
  const ushort_t* Bu = (const ushort_t*)Wt;
  f32x4 acc[MT][NT] = {};

  STAGEG(0, 0)
  asm volatile("s_waitcnt vmcnt(0)" ::: "memory");
  __builtin_amdgcn_s_barrier();

  int cur = 0;
  for (int k0 = 0; k0 < K; k0 += 64) {
    if (k0 + 64 < K) STAGEG(cur ^ 1, k0 + 64)
    #pragma unroll
    for (int kh = 0; kh < 2; ++kh) {
      short8v af[MT], bfr[NT];
      #pragma unroll
      for (int mt = 0; mt < MT; ++mt) {
        int row = wr * WMH + mt * 16 + ln;
        af[mt] = *(const short8v*)&Al[cur][row * 64 + (((kh * 4 + lg) ^ (row & 7))) * 8];
      }
      #pragma unroll
      for (int nt = 0; nt < NT; ++nt) {
        int row = wc * WNH + nt * 16 + ln;
        bfr[nt] = *(const short8v*)&Bl[cur][row * 64 + (((kh * 4 + lg) ^ (row & 7))) * 8];
      }
      #pragma unroll
      for (int mt = 0; mt < MT; ++mt)
        #pragma unroll
        for (int nt = 0; nt < NT; ++nt)
          acc[mt][nt] = __builtin_amdgcn_mfma_f32_16x16x32_bf16(af[mt], bfr[nt], acc[mt][nt], 0, 0, 0);
    }
    asm volatile("s_waitcnt vmcnt(0)" ::: "memory");
    __builtin_amdgcn_s_barrier();
    cur ^= 1;
  }

  #pragma unroll
  for (int mt = 0; mt < MT; ++mt)
    #pragma unroll
    for (int nt = 0; nt < NT; ++nt) {
      const int colbase = bn + wc * WNH + nt * 16;
      const int sec = colbase >> 8;          // 0=Q 1=K 2=V 3=G (uniform per block)
      const int c = (colbase & 255) + ln;
      const int grow0 = bm + wr * WMH + mt * 16 + lg * 4;
      if (sec <= 1) {
        const int jj = (c & 31) >> 1;
        const float l2g = l2g_of(c >> 5);
        #pragma unroll
        for (int r = 0; r < 4; ++r) {
          const int grow = grow0 + r;
          const int s = grow & (SS - 1);
          float v = acc[mt][nt][r];
          float pv = __shfl_xor(v, 1);
          float scv = tsc[s * 16 + jj];
          if (sec == 1) scv = 1.0f / scv;
          float ce = tcs[s * 16 + jj] * scv, se = tsn[s * 16 + jj] * scv;
          float o = (ln & 1) ? (v * ce + pv * se) : (v * ce - pv * se);
          if (sec == 0) o *= exp2f(l2g * (float)s);   // fold decay g^n into Q
          bf16* dst = (sec == 0) ? (bf16*)o0 : (bf16*)o1;
          dst[(size_t)grow * DD + c] = __float2bfloat16(o);
        }
      } else if (sec == 2) {
        // V transposed + fold g^(-m): vT[(b*8+h)*32 + d][s] = v(m=s,d) * g^(-s)
        const int b = grow0 >> 11, s0 = grow0 & (SS - 1);
        const int h = c >> 5, d = c & 31;
        const float nl2g = -l2g_of(h);                // positive
        float v0 = acc[mt][nt][0] * exp2f(nl2g * (float)(s0 + 0));
        float v1 = acc[mt][nt][1] * exp2f(nl2g * (float)(s0 + 1));
        float v2 = acc[mt][nt][2] * exp2f(nl2g * (float)(s0 + 2));
        float v3 = acc[mt][nt][3] * exp2f(nl2g * (float)(s0 + 3));
        uint2 pk;
        pk.x = cvtpk(v0, v1);
        pk.y = cvtpk(v2, v3);
        *(uint2*)((ushort_t*)o2 + ((size_t)(b * 8 + h) * 32 + d) * SS + s0) = pk;
      } else {
        #pragma unroll
        for (int r = 0; r < 4; ++r)
          ((float*)o3)[(size_t)(grow0 + r) * DD + c] = acc[mt][nt][r];
      }
    }
}

// ---------------- FFN mega-kernel v2: per-wave B staging, 48KB LDS, 3 blocks/CU ----------------
// BM=16 rows/block, grid MM/16=512, 4 waves; wave w owns cols [w*64, w*64+64).
// Bs: per-wave-private 64x64 single buffer (wave-local vmcnt, NO per-step barriers).
template<bool LAST>
__global__ __launch_bounds__(256, 3) void ffn_mega(
    const bf16* __restrict__ ubg, const bf16* __restrict__ wotg,
    const bf16* __restrict__ w1tg, const bf16* __restrict__ w2tg,
    const float* __restrict__ b1v, const float* __restrict__ b2v,
    const float* __restrict__ resin,
    float* __restrict__ yres, bf16* __restrict__ xn, float* __restrict__ dout,
    const float* __restrict__ l2w, const float* __restrict__ l2b,
    const float* __restrict__ lfw, const float* __restrict__ lfb,
    const float* __restrict__ l1w, const float* __restrict__ l1b)
{
  __shared__ __align__(16) ushort_t Bs[4][4096];       // 32 KB: per-wave 64x64
  __shared__ __align__(16) ushort_t AX[4096];          // 8 KB: Wo-A dbuf (2x1024) then Xs[16][256]
  __shared__ __align__(16) ushort_t Us[4096];          // 8 KB: LN red scratch + GELU chunk [16][256]

  const int bm = blockIdx.x * 16;
  const int tid = threadIdx.x;
  const int lane = tid & 63, w = tid >> 6;
  const int lg = lane >> 4, ln = lane & 15;
  const int row0 = lg * 4;
  const ushort_t* ubu  = (const ushort_t*)ubg;
  const ushort_t* wotu = (const ushort_t*)wotg;
  const ushort_t* w1tu = (const ushort_t*)w1tg;
  const ushort_t* w2tu = (const ushort_t*)w2tg;
  float* red = (float*)Us;   // [4 waves][16 rows][2], 512 B

  // early residual prefetch (consumed after Wo phase)
  float resv[4][4];
  #pragma unroll
  for (int nt = 0; nt < 4; ++nt) {
    const int gcol = w * 64 + nt * 16 + ln;
    #pragma unroll
    for (int r = 0; r < 4; ++r)
      resv[nt][r] = resin[(size_t)(bm + row0 + r) * DD + gcol];
  }

  // wave-private B stage: rows (nbase + w*64 + r) of Wt[n][k], k-slice koff..+64
  #define STAGEBW(base, stride, nbase, koff) { \
    _Pragma("unroll") \
    for (int i = 0; i < 8; ++i) { \
      int slot = i * 64 + lane; int r = slot >> 3, blk = slot & 7; \
      gload_lds16((base) + (size_t)((nbase) + w * 64 + r) * (stride) + (koff) + ((blk ^ (r & 7))) * 8, &Bs[w][slot * 8]); \
    } }
  #define STAGEA(buf, koff) { \
    if (tid < 128) { int rr = tid >> 3, blk = tid & 7; \
      gload_lds16(ubu + (size_t)(bm + rr) * DD + (koff) + ((blk ^ (rr & 7))) * 8, &AX[(buf) * 1024 + tid * 8]); } }
  #define WAVEWAIT asm volatile("s_waitcnt vmcnt(0)" ::: "memory");

  // ---- phase 1: Wo GEMM (K=256, 4 steps; A dbuf shared, B per-wave) ----
  STAGEA(0, 0)
  STAGEBW(wotu, 256, 0, 0)
  WAVEWAIT
  __builtin_amdgcn_s_barrier();
  int cur = 0;
  f32x4 accw[4] = {};
  #pragma unroll
  for (int s = 0; s < 4; ++s) {
    if (s < 3) STAGEA(cur ^ 1, (s + 1) * 64)
    #pragma unroll
    for (int kh = 0; kh < 2; ++kh) {
      short8v af = *(const short8v*)&AX[cur * 1024 + ln * 64 + (((kh * 4 + lg) ^ (ln & 7))) * 8];
      #pragma unroll
      for (int nt = 0; nt < 4; ++nt) {
        int r = nt * 16 + ln;
        short8v bf_ = *(const short8v*)&Bs[w][r * 64 + (((kh * 4 + lg) ^ (r & 7))) * 8];
        accw[nt] = __builtin_amdgcn_mfma_f32_16x16x32_bf16(af, bf_, accw[nt], 0, 0, 0);
      }
    }
    if (s < 3) STAGEBW(wotu, 256, 0, (s + 1) * 64)
    WAVEWAIT
    __builtin_amdgcn_s_barrier();
    cur ^= 1;
  }

  // ---- v = Wo + residual; LN2; write Xs (bf16, swizzled A-layout) ----
  float v[4][4];
  #pragma unroll
  for (int nt = 0; nt < 4; ++nt)
    #pragma unroll
    for (int r = 0; r < 4; ++r) v[nt][r] = accw[nt][r] + resv[nt][r];
  float mu[4], rsg[4];
  {
    #pragma unroll
    for (int r = 0; r < 4; ++r) {
      float s1 = 0.f, s2 = 0.f;
      #pragma unroll
      for (int nt = 0; nt < 4; ++nt) { s1 += v[nt][r]; s2 += v[nt][r] * v[nt][r]; }
      #pragma unroll
      for (int m = 8; m >= 1; m >>= 1) { s1 += __shfl_xor(s1, m); s2 += __shfl_xor(s2, m); }
      if (ln == 0) { red[(w * 16 + row0 + r) * 2] = s1; red[(w * 16 + row0 + r) * 2 + 1] = s2; }
    }
    __syncthreads();
    #pragma unroll
    for (int r = 0; r < 4; ++r) {
      float S = 0.f, S2 = 0.f;
      #pragma unroll
      for (int ww = 0; ww < 4; ++ww) { S += red[(ww * 16 + row0 + r) * 2]; S2 += red[(ww * 16 + row0 + r) * 2 + 1]; }
      float m_ = S * (1.0f / 256.0f);
      mu[r] = m_; rsg[r] = rsqrtf(S2 * (1.0f / 256.0f) - m_ * m_ + 1e-5f);
    }
  }
  #pragma unroll
  for (int nt = 0; nt < 4; ++nt) {
    const int gcol = w * 64 + nt * 16 + ln;
    const float lwv = l2w[gcol], lbv = l2b[gcol];
    const int off = nt * 16 + ln, blk = off >> 3, sub = off & 7;
    #pragma unroll
    for (int r = 0; r < 4; ++r) {
      const int row = row0 + r;
      float xv = (v[nt][r] - mu[r]) * rsg[r] * lwv + lbv;
      AX[row * 256 + w * 64 + ((blk ^ (row & 7)) << 3) + sub] = f2b1(xv);
    }
  }
  __syncthreads();

  // ---- phases 2..9: 4 chunks of {FFN1 (K=256) -> GELU -> FFN2 partial (K-slice 256)} ----
  // Within each GEMM: per-wave B stage + wave-local vmcnt, NO barriers between steps.
  f32x4 acc2[4] = {};
  #pragma unroll
  for (int c = 0; c < 4; ++c) {
    f32x4 acc1[4] = {};
    #pragma unroll
    for (int s = 0; s < 4; ++s) {
      STAGEBW(w1tu, 256, c * 256, s * 64)
      WAVEWAIT
      #pragma unroll
      for (int kh = 0; kh < 2; ++kh) {
        short8v af = *(const short8v*)&AX[ln * 256 + s * 64 + (((kh * 4 + lg) ^ (ln & 7))) * 8];
        #pragma unroll
        for (int nt = 0; nt < 4; ++nt) {
          int r = nt * 16 + ln;
          short8v bf_ = *(const short8v*)&Bs[w][r * 64 + (((kh * 4 + lg) ^ (r & 7))) * 8];
          acc1[nt] = __builtin_amdgcn_mfma_f32_16x16x32_bf16(af, bf_, acc1[nt], 0, 0, 0);
        }
      }
    }
    // barrier: previous chunk's FFN2 cross-wave Us reads must be done before GELU overwrite
    __syncthreads();
    // GELU -> Us (bf16, swizzled A-layout); each wave writes its own 64-col slice
    #pragma unroll
    for (int nt = 0; nt < 4; ++nt) {
      const int gcol1 = c * 256 + w * 64 + nt * 16 + ln;
      const float bb = b1v[gcol1];
      const int off = nt * 16 + ln, blk = off >> 3, sub = off & 7;
      #pragma unroll
      for (int r = 0; r < 4; ++r) {
        const int row = row0 + r;
        float t = acc1[nt][r] + bb;
        t = 0.5f * t * (1.0f + erff(t * 0.70710678118654752f));
        Us[row * 256 + w * 64 + ((blk ^ (row & 7)) << 3) + sub] = f2b1(t);
      }
    }
    __syncthreads();
    #pragma unroll
    for (int s = 0; s < 4; ++s) {
      STAGEBW(w2tu, 1024, 0, c * 256 + s * 64)
      WAVEWAIT
      #pragma unroll
      for (int kh = 0; kh < 2; ++kh) {
        short8v af = *(const short8v*)&Us[ln * 256 + s * 64 + (((kh * 4 + lg) ^ (ln & 7))) * 8];
        #pragma unroll
        for (int nt = 0; nt < 4; ++nt) {
          int r = nt * 16 + ln;
          short8v bf_ = *(const short8v*)&Bs[w][r * 64 + (((kh * 4 + lg) ^ (r & 7))) * 8];
          acc2[nt] = __builtin_amdgcn_mfma_f32_16x16x32_bf16(af, bf_, acc2[nt], 0, 0, 0);
        }
      }
    }
  }
  __syncthreads();   // all FFN2 Us reads done before epilogue red writes

  // ---- epilogue: f = FFN2 + b2 + v; LNf; (LAST: dout) else (yres, LN1' -> xn) ----
  float f[4][4];
  #pragma unroll
  for (int nt = 0; nt < 4; ++nt) {
    const int gcol = w * 64 + nt * 16 + ln;
    const float bb = b2v[gcol];
    #pragma unroll
    for (int r = 0; r < 4; ++r) f[nt][r] = acc2[nt][r] + bb + v[nt][r];
  }
  {
    #pragma unroll
    for (int r = 0; r < 4; ++r) {
      float s1 = 0.f, s2 = 0.f;
      #pragma unroll
      for (int nt = 0; nt < 4; ++nt) { s1 += f[nt][r]; s2 += f[nt][r] * f[nt][r]; }
      #pragma unroll
      for (int m = 8; m >= 1; m >>= 1) { s1 += __shfl_xor(s1, m); s2 += __shfl_xor(s2, m); }
      if (ln == 0) { red[(w * 16 + row0 + r) * 2] = s1; red[(w * 16 + row0 + r) * 2 + 1] = s2; }
    }
    __syncthreads();
    #pragma unroll
    for (int r = 0; r < 4; ++r) {
      float S = 0.f, S2 = 0.f;
      #pragma unroll
      for (int ww = 0; ww < 4; ++ww) { S += red[(ww * 16 + row0 + r) * 2]; S2 += red[(ww * 16 + row0 + r) * 2 + 1]; }
      float m_ = S * (1.0f / 256.0f);
      mu[r] = m_; rsg[r] = rsqrtf(S2 * (1.0f / 256.0f) - m_ * m_ + 1e-5f);
    }
  }
  float u[4][4];
  #pragma unroll
  for (int nt = 0; nt < 4; ++nt) {
    const int gcol = w * 64 + nt * 16 + ln;
    const float lwv = lfw[gcol], lbv = lfb[gcol];
    #pragma unroll
    for (int r = 0; r < 4; ++r)
      u[nt][r] = (f[nt][r] - mu[r]) * rsg[r] * lwv + lbv;
  }
  if constexpr (LAST) {
    #pragma unroll
    for (int nt = 0; nt < 4; ++nt) {
      const int gcol = w * 64 + nt * 16 + ln;
      #pragma unroll
      for (int r = 0; r < 4; ++r)
        dout[(size_t)(bm + row0 + r) * DD + gcol] = u[nt][r];
    }
  } else {
    __syncthreads();
    #pragma unroll
    for (int r = 0; r < 4; ++r) {
      float s1 = 0.f, s2 = 0.f;
      #pragma unroll
      for (int nt = 0; nt < 4; ++nt) { s1 += u[nt][r]; s2 += u[nt][r] * u[nt][r]; }
      #pragma unroll
      for (int m = 8; m >= 1; m >>= 1) { s1 += __shfl_xor(s1, m); s2 += __shfl_xor(s2, m); }
      if (ln == 0) { red[(w * 16 + row0 + r) * 2] = s1; red[(w * 16 + row0 + r) * 2 + 1] = s2; }
    }
    __syncthreads();
    float mu2[4], rs2[4];
    #pragma unroll
    for (int r = 0; r < 4; ++r) {
      float S = 0.f, S2 = 0.f;
      #pragma unroll
      for (int ww = 0; ww < 4; ++ww) { S += red[(ww * 16 + row0 + r) * 2]; S2 += red[(ww * 16 + row0 + r) * 2 + 1]; }
      float m_ = S * (1.0f / 256.0f);
      mu2[r] = m_; rs2[r] = rsqrtf(S2 * (1.0f / 256.0f) - m_ * m_ + 1e-5f);
    }
    #pragma unroll
    for (int nt = 0; nt < 4; ++nt) {
      const int gcol = w * 64 + nt * 16 + ln;
      const float lwv = l1w[gcol], lbv = l1b[gcol];
      #pragma unroll
      for (int r = 0; r < 4; ++r) {
        const size_t idx = (size_t)(bm + row0 + r) * DD + gcol;
        yres[idx] = u[nt][r];
        xn[idx] = __float2bfloat16((u[nt][r] - mu2[r]) * rs2[r] * lwv + lbv);
      }
    }
  }
  #undef STAGEBW
  #undef STAGEA
  #undef WAVEWAIT
}

// ---------------- Retention + fused GroupNorm/SiLU-gate ----------------
// Decay pre-folded: q *= g^n, vT *= g^(-m). Inner loop: raw QK -> pack -> PV.
__global__ __launch_bounds__(256) void attn_k(const bf16* __restrict__ qg, const bf16* __restrict__ kg,
    const bf16* __restrict__ vtg, const float* __restrict__ gbuf,
    const float* __restrict__ gnw, const float* __restrict__ gnb, bf16* __restrict__ ub)
{
  __shared__ __align__(16) ushort_t Kl[2][64 * 32];      // [m][k], blk ^= m&3
  __shared__ __align__(16) ushort_t Vl[2][32 * 64];      // [d][m], blk ^= d&7
  __shared__ __align__(16) unsigned int Pl[4][512];      // per wave: P^T[n=ln][64 m] bf16

  const int bh = blockIdx.x;
  const int b = bh >> 3, h = bh & (HH - 1);
  const int n0 = ((int)gridDim.y - 1 - (int)blockIdx.y) * 64;
  const int tid = threadIdx.x;
  const int w = tid >> 6, lane = tid & 63;
  const int lg = lane >> 4, ln = lane & 15;

  const size_t base = (size_t)b * SS * DD + h * HDD;
  const ushort_t* qp = (const ushort_t*)qg + base;
  const ushort_t* kp = (const ushort_t*)kg + base;
  const ushort_t* vtp = (const ushort_t*)vtg + (size_t)(b * 8 + h) * 32 * SS;

  const int n = n0 + w * 16 + ln;
  const short8v qf = *(const short8v*)(qp + (size_t)n * DD + lg * 8);

  const float l2g = l2g_of(h);                     // negative; only for window calc
  f32x4 acc0 = {0,0,0,0}, acc1 = {0,0,0,0};

  const int Wwin = (int)(20.0f / (-l2g)) + 1;
  int m_lo = 0;
  if (n0 > Wwin) m_lo = ((n0 - Wwin) >> 6) << 6;

  const int Krow = tid >> 2, Kc8 = tid & 3;
  const int Vrow = tid >> 3, Vc8 = tid & 7;

  #define STAGE(buf, m0s) { \
    gload_lds16(kp + (size_t)((m0s) + Krow) * DD + ((Kc8 ^ (Krow & 3)) * 8), &Kl[buf][tid * 8]); \
    gload_lds16(vtp + (size_t)Vrow * SS + (m0s) + ((Vc8 ^ (Vrow & 7)) * 8), &Vl[buf][tid * 8]); }

  STAGE(0, m_lo)
  asm volatile("s_waitcnt vmcnt(0)" ::: "memory");
  __builtin_amdgcn_s_barrier();

  int cur = 0;
  for (int m0 = m_lo; m0 <= n0; m0 += 64) {
    if (m0 < n0) STAGE(cur ^ 1, m0 + 64)
    const bool diag = (m0 == n0);
    __builtin_amdgcn_s_setprio(1);
    #pragma unroll
    for (int mt = 0; mt < 4; ++mt) {
      const int krow = mt * 16 + ln;
      short8v kf = *(const short8v*)&Kl[cur][krow * 32 + ((lg ^ (krow & 3)) << 3)];
      f32x4 z = {0,0,0,0};
      f32x4 pa = __builtin_amdgcn_mfma_f32_16x16x32_bf16(kf, qf, z, 0, 0, 0);
      float v0 = pa[0], v1 = pa[1], v2 = pa[2], v3 = pa[3];
      if (diag) {
        const int m = n0 + mt * 16 + lg * 4;
        v0 = (n < m)     ? 0.f : v0;
        v1 = (n < m + 1) ? 0.f : v1;
        v2 = (n < m + 2) ? 0.f : v2;
        v3 = (n < m + 3) ? 0.f : v3;
      }
      uint2 pk;
      pk.x = cvtpk(v0, v1);
      pk.y = cvtpk(v2, v3);
      const int blk = (mt * 2 + (lg >> 1)) ^ (ln & 7);
      *(uint2*)&Pl[w][ln * 32 + blk * 4 + (lg & 1) * 2] = pk;
    }
    #pragma unroll
    for (int hh = 0; hh < 2; ++hh) {
      const int pblk = (hh * 4 + lg) ^ (ln & 7);
      uint4v pw = *(const uint4v*)&Pl[w][ln * 32 + pblk * 4];
      short8v pf = __builtin_bit_cast(short8v, pw);
      #pragma unroll
      for (int dt = 0; dt < 2; ++dt) {
        const int d = dt * 16 + ln;
        short8v vf = *(const short8v*)&Vl[cur][d * 64 + (((hh * 4 + lg) ^ (d & 7)) << 3)];
        if (dt == 0) acc0 = __builtin_amdgcn_mfma_f32_16x16x32_bf16(vf, pf, acc0, 0, 0, 0);
        else         acc1 = __builtin_amdgcn_mfma_f32_16x16x32_bf16(vf, pf, acc1, 0, 0, 0);
      }
    }
    __builtin_amdgcn_s_setprio(0);
    asm volatile("s_waitcnt vmcnt(0)" ::: "memory");
    __builtin_amdgcn_s_barrier();
    cur ^= 1;
  }
  #undef STAGE

  // ---- fused GroupNorm (per head) + SiLU gate ----
  float gwv[8], gbv[8];
  #pragma unroll
  for (int dt = 0; dt < 2; ++dt) {
    f32x4 a = *(const f32x4*)&gnw[h * 32 + dt * 16 + lg * 4];
    f32x4 c = *(const f32x4*)&gnb[h * 32 + dt * 16 + lg * 4];
    #pragma unroll
    for (int r = 0; r < 4; ++r) { gwv[dt * 4 + r] = a[r]; gbv[dt * 4 + r] = c[r]; }
  }
  float s = 0.f;
  #pragma unroll
  for (int r = 0; r < 4; ++r) s += acc0[r] + acc1[r];
  s += __shfl_xor(s, 16); s += __shfl_xor(s, 32);
  const float mu = s * (1.0f / 32.0f);
  float s2 = 0.f;
  #pragma unroll
  for (int r = 0; r < 4; ++r) { float d0 = acc0[r] - mu, d1 = acc1[r] - mu; s2 += d0 * d0 + d1 * d1; }
  s2 += __shfl_xor(s2, 16); s2 += __shfl_xor(s2, 32);
  const float rs = rsqrtf(s2 * (1.0f / 32.0f) + 1e-5f);
  const size_t rowoff = ((size_t)b * SS + n) * DD + h * 32;
  #pragma unroll
  for (int dt = 0; dt < 2; ++dt) {
    f32x4 yv = dt ? acc1 : acc0;
    f32x4 gv = *(const f32x4*)&gbuf[rowoff + dt * 16 + lg * 4];
    float o0, o1, o2, o3;
    {
      float yn0 = (yv[0] - mu) * rs * gwv[dt * 4 + 0] + gbv[dt * 4 + 0];
      float yn1 = (yv[1] - mu) * rs * gwv[dt * 4 + 1] + gbv[dt * 4 + 1];
      float yn2 = (yv[2] - mu) * rs * gwv[dt * 4 + 2] + gbv[dt * 4 + 2];
      float yn3 = (yv[3] - mu) * rs * gwv[dt * 4 + 3] + gbv[dt * 4 + 3];
      o0 = gv[0] / (1.0f + expf(-gv[0])) * yn0;
      o1 = gv[1] / (1.0f + expf(-gv[1])) * yn1;
      o2 = gv[2] / (1.0f + expf(-gv[2])) * yn2;
      o3 = gv[3] / (1.0f + expf(-gv[3])) * yn3;
    }
    uint2 pk;
    pk.x = cvtpk(o0, o1);
    pk.y = cvtpk(o2, o3);
    *(uint2*)((ushort_t*)ub + rowoff + dt * 16 + lg * 4) = pk;
  }
}

extern "C" void kernel_launch(void* const* d_in, const int* in_sizes, int n_in,
                              void* d_out, int out_size, void* d_ws, size_t ws_size,
                              hipStream_t stream)
{
  const float* X    = (const float*)d_in[0];
  const float* Wq   = (const float*)d_in[1];
  const float* Wk   = (const float*)d_in[2];
  const float* Wv   = (const float*)d_in[3];
  const float* Wg   = (const float*)d_in[4];
  const float* Wo   = (const float*)d_in[5];
  const float* gnw  = (const float*)d_in[6];
  const float* gnb  = (const float*)d_in[7];
  const float* ln1w = (const float*)d_in[8];
  const float* ln1b = (const float*)d_in[9];
  const float* ln2w = (const float*)d_in[10];
  const float* ln2b = (const float*)d_in[11];
  const float* w1   = (const float*)d_in[12];
  const float* b1   = (const float*)d_in[13];
  const float* w2   = (const float*)d_in[14];
  const float* b2   = (const float*)d_in[15];
  const float* lnfw = (const float*)d_in[16];
  const float* lnfb = (const float*)d_in[17];

  // Workspace (~40 MiB)
  char* p = (char*)d_ws;
  const size_t AF  = (size_t)MM * DD * sizeof(float);  // 8 MiB
  const size_t ABF = (size_t)MM * DD * sizeof(bf16);   // 4 MiB
  bf16*  xn   = (bf16*)p;  p += ABF;
  bf16*  qb   = (bf16*)p;  p += ABF;
  bf16*  kb   = (bf16*)p;  p += ABF;
  bf16*  vT   = (bf16*)p;  p += ABF;   // [B][H][32][S], pre-scaled by g^(-m)
  bf16*  ub   = (bf16*)p;  p += ABF;
  float* gbuf = (float*)p; p += AF;
  float* yres = (float*)p; p += AF;
  bf16*  wqkvgt = (bf16*)p; p += (size_t)2 * 1024 * 256 * sizeof(bf16);
  bf16*  wot    = (bf16*)p; p += (size_t)2 * 256 * 256 * sizeof(bf16);
  bf16*  w1t    = (bf16*)p; p += (size_t)2 * 1024 * 256 * sizeof(bf16);
  bf16*  w2t    = (bf16*)p; p += (size_t)2 * 256 * 1024 * sizeof(bf16);
  float* tsn  = (float*)p; p += SS * 16 * sizeof(float);
  float* tcs  = (float*)p; p += SS * 16 * sizeof(float);
  float* tsc  = (float*)p; p += SS * 16 * sizeof(float);

  {
    WDescA da;
    for (int l = 0; l < 2; ++l) {
      da.d[l * 7 + 0] = { Wq + (size_t)l * 65536, wqkvgt + (size_t)l * 262144 + 0 * 65536, 256, 256 };
      da.d[l * 7 + 1] = { Wk + (size_t)l * 65536, wqkvgt + (size_t)l * 262144 + 1 * 65536, 256, 256 };
      da.d[l * 7 + 2] = { Wv + (size_t)l * 65536, wqkvgt + (size_t)l * 262144 + 2 * 65536, 256, 256 };
      da.d[l * 7 + 3] = { Wg + (size_t)l * 65536, wqkvgt + (size_t)l * 262144 + 3 * 65536, 256, 256 };
      da.d[l * 7 + 4] = { Wo + (size_t)l * 65536, wot + (size_t)l * 65536, 256, 256 };
      da.d[l * 7 + 5] = { w1 + (size_t)l * 262144, w1t + (size_t)l * 262144, 256, 1024 };
      da.d[l * 7 + 6] = { w2 + (size_t)l * 262144, w2t + (size_t)l * 262144, 1024, 256 };
    }
    da.tsn = tsn; da.tcs = tcs; da.tsc = tsc;
    wconv_k<<<dim3(32, 32, 15), dim3(32, 8), 0, stream>>>(da);
  }

  // layer 0 LN1 (layer 1's LN1 is fused into layer 0's mega epilogue)
  ln_k<bf16><<<dim3(MM), 256, 0, stream>>>(X, ln1w, ln1b, xn);

  for (int l = 0; l < LYR; ++l) {
    mgemm_k<64, 128, DD, E_QKVG><<<dim3(MM / 64, 1024 / 128), 256, 0, stream>>>(
        xn, wqkvgt + (size_t)l * 262144, qb, kb, vT, gbuf, tsn, tcs, tsc);
    attn_k<<<dim3(BB * HH, SS / 64), 256, 0, stream>>>(qb, kb, vT, gbuf, gnw + l * DD, gnb + l * DD, ub);
    if (l == LYR - 1) {
      ffn_mega<true><<<dim3(MM / 16), 256, 0, stream>>>(
          ub, wot + (size_t)l * 65536, w1t + (size_t)l * 262144, w2t + (size_t)l * 262144,
          b1 + l * FFD, b2 + l * DD, (l == 0) ? X : yres,
          nullptr, nullptr, (float*)d_out,
          ln2w + l * DD, ln2b + l * DD, lnfw, lnfb, nullptr, nullptr);
    } else {
      ffn_mega<false><<<dim3(MM / 16), 256, 0, stream>>>(
          ub, wot + (size_t)l * 65536, w1t + (size_t)l * 262144, w2t + (size_t)l * 262144,
          b1 + l * FFD, b2 + l * DD, (l == 0) ? X : yres,
          yres, xn, nullptr,
          ln2w + l * DD, ln2b + l * DD, lnfw, lnfb, ln1w + (l + 1) * DD, ln1b + (l + 1) * DD);
    }
  }
}

// Round 15
// 185.084 us; speedup vs baseline: 1.0838x; 1.0372x over previous
//
#include <hip/hip_runtime.h>
#include <hip/hip_bf16.h>

typedef __hip_bfloat16 bf16;
typedef unsigned short ushort_t;
typedef __attribute__((ext_vector_type(8))) short short8v;
typedef __attribute__((ext_vector_type(4))) float f32x4;
typedef __attribute__((ext_vector_type(4))) unsigned int uint4v;

// RetNet block: L=2, B=4, S=2048, D=256, H=8, HD=32, FFN*D=1024
#define LYR 2
#define BB 4
#define SS 2048
#define DD 256
#define HH 8
#define HDD 32
#define FFD 1024
#define MM (BB*SS)   // 8192 tokens

__device__ __forceinline__ unsigned int cvtpk(float lo, float hi) {
  unsigned int r;
  asm("v_cvt_pk_bf16_f32 %0, %1, %2" : "=v"(r) : "v"(lo), "v"(hi));
  return r;
}
__device__ __forceinline__ ushort_t f2b1(float x) { return (ushort_t)cvtpk(x, x); }

__device__ __forceinline__ void gload_lds16(const void* g, void* l) {
  __builtin_amdgcn_global_load_lds((const __attribute__((address_space(1))) void*)g,
                                   (__attribute__((address_space(3))) void*)l, 16, 0, 0);
}

// decay exponent: l2g(h) = log2(1 - exp(log(1/32) + h*(log(1/512)-log(1/32))/7))  (negative)
__device__ __forceinline__ float l2g_of(int h) {
  return log2f(1.0f - expf(-3.4657359028f - 0.3960841187f * (float)h));
}

// ---------------- weight transpose+convert + xPos tables (z==14) ----------------
struct WDesc { const float* src; bf16* dst; int K; int N; };
struct WDescA { WDesc d[14]; float* tsn; float* tcs; float* tsc; };
__global__ __launch_bounds__(256) void wconv_k(WDescA da) {
  if (blockIdx.z == 14) {
    int i = (blockIdx.y * 32 + blockIdx.x) * 256 + threadIdx.y * 32 + threadIdx.x;
    if (i >= SS * 16) return;
    int s = i >> 4, j = i & 15;
    float sv = (2.0f * (float)j + 0.4f * (float)HDD) / (1.4f * (float)HDD);
    da.tsc[i] = powf(sv, (float)s * (1.0f / 512.0f));
    float inv_freq = powf(10000.0f, -(float)j * (1.0f / 16.0f));
    float ang = (float)s * inv_freq;
    da.tsn[i] = sinf(ang);
    da.tcs[i] = cosf(ang);
    return;
  }
  WDesc dd = da.d[blockIdx.z];
  int n0 = blockIdx.x * 32, k0 = blockIdx.y * 32;
  if (n0 >= dd.N || k0 >= dd.K) return;
  __shared__ float t[32][33];
  int tx = threadIdx.x, ty = threadIdx.y;   // 32 x 8
  #pragma unroll
  for (int i = 0; i < 32; i += 8) t[ty + i][tx] = dd.src[(size_t)(k0 + ty + i) * dd.N + n0 + tx];
  __syncthreads();
  #pragma unroll
  for (int i = 0; i < 32; i += 8) dd.dst[(size_t)(n0 + ty + i) * dd.K + k0 + tx] = __float2bfloat16(t[tx][ty + i]);
}

// ---------------- LayerNorm over D=256 (one block per row), f32 in, OT out ----------------
template<typename OT>
__global__ __launch_bounds__(256) void ln_k(const float* __restrict__ in, const float* __restrict__ w,
    const float* __restrict__ b, OT* __restrict__ out)
{
  int row = blockIdx.x, t = threadIdx.x;
  float v = in[(size_t)row * DD + t];
  __shared__ float red[4];
  float s = v;
  #pragma unroll
  for (int m = 32; m >= 1; m >>= 1) s += __shfl_xor(s, m);
  if ((t & 63) == 0) red[t >> 6] = s;
  __syncthreads();
  float mu = (red[0] + red[1] + red[2] + red[3]) * (1.0f / 256.0f);
  float d = v - mu;
  float s2 = d * d;
  #pragma unroll
  for (int m = 32; m >= 1; m >>= 1) s2 += __shfl_xor(s2, m);
  __syncthreads();
  if ((t & 63) == 0) red[t >> 6] = s2;
  __syncthreads();
  float var = (red[0] + red[1] + red[2] + red[3]) * (1.0f / 256.0f);
  float o = d * rsqrtf(var + 1e-5f) * w[t] + b[t];
  if constexpr (sizeof(OT) == 2) out[(size_t)row * DD + t] = __float2bfloat16(o);
  else                           out[(size_t)row * DD + t] = o;
}

#define STAGEG(buf, k0s) { \
    _Pragma("unroll") \
    for (int i = 0; i < BM / 32; ++i) { \
      int slot = i * 256 + tid; int row = slot >> 3, blk = slot & 7; \
      gload_lds16(Au + (size_t)(bm + row) * K + (k0s) + ((blk ^ (row & 7))) * 8, &Al[buf][slot * 8]); \
    } \
    _Pragma("unroll") \
    for (int i = 0; i < BN / 32; ++i) { \
      int slot = i * 256 + tid; int row = slot >> 3, blk = slot & 7; \
      gload_lds16(Bu + (size_t)(bn + row) * K + (k0s) + ((blk ^ (row & 7))) * 8, &Bl[buf][slot * 8]); \
    } }

// ---------------- bf16 MFMA GEMM (QKVG projection), double-buffered ----------------
enum { E_QKVG = 0 };

template<int BM, int BN, int K, int EPI>
__global__ __launch_bounds__(256) void mgemm_k(const bf16* __restrict__ Ag, const bf16* __restrict__ Wt,
    void* o0, void* o1, void* o2, void* o3,
    const float* __restrict__ tsn, const float* __restrict__ tcs, const float* __restrict__ tsc)
{
  constexpr int MT = BM / 32, NT = BN / 32;
  constexpr int WMH = BM / 2, WNH = BN / 2;
  __shared__ __align__(16) ushort_t Al[2][BM * 64];
  __shared__ __align__(16) ushort_t Bl[2][BN * 64];
  const int bm = blockIdx.x * BM;
  const int bn = blockIdx.y * BN;
  const int tid = threadIdx.x;
  const int lane = tid & 63, w = tid >> 6;
  const int lg = lane >> 4, ln = lane & 15;
  const int wr = w >> 1, wc = w & 1;
  const ushort_t* Au = (const ushort_t*)Ag;
  const ushort_t* Bu = (const ushort_t*)Wt;
  f32x4 acc[MT][NT] = {};

  STAGEG(0, 0)
  asm volatile("s_waitcnt vmcnt(0)" ::: "memory");
  __builtin_amdgcn_s_barrier();

  int cur = 0;
  for (int k0 = 0; k0 < K; k0 += 64) {
    if (k0 + 64 < K) STAGEG(cur ^ 1, k0 + 64)
    #pragma unroll
    for (int kh = 0; kh < 2; ++kh) {
      short8v af[MT], bfr[NT];
      #pragma unroll
      for (int mt = 0; mt < MT; ++mt) {
        int row = wr * WMH + mt * 16 + ln;
        af[mt] = *(const short8v*)&Al[cur][row * 64 + (((kh * 4 + lg) ^ (row & 7))) * 8];
      }
      #pragma unroll
      for (int nt = 0; nt < NT; ++nt) {
        int row = wc * WNH + nt * 16 + ln;
        bfr[nt] = *(const short8v*)&Bl[cur][row * 64 + (((kh * 4 + lg) ^ (row & 7))) * 8];
      }
      #pragma unroll
      for (int mt = 0; mt < MT; ++mt)
        #pragma unroll
        for (int nt = 0; nt < NT; ++nt)
          acc[mt][nt] = __builtin_amdgcn_mfma_f32_16x16x32_bf16(af[mt], bfr[nt], acc[mt][nt], 0, 0, 0);
    }
    asm volatile("s_waitcnt vmcnt(0)" ::: "memory");
    __builtin_amdgcn_s_barrier();
    cur ^= 1;
  }

  #pragma unroll
  for (int mt = 0; mt < MT; ++mt)
    #pragma unroll
    for (int nt = 0; nt < NT; ++nt) {
      const int colbase = bn + wc * WNH + nt * 16;
      const int sec = colbase >> 8;          // 0=Q 1=K 2=V 3=G (uniform per block)
      const int c = (colbase & 255) + ln;
      const int grow0 = bm + wr * WMH + mt * 16 + lg * 4;
      if (sec <= 1) {
        const int jj = (c & 31) >> 1;
        const float l2g = l2g_of(c >> 5);
        #pragma unroll
        for (int r = 0; r < 4; ++r) {
          const int grow = grow0 + r;
          const int s = grow & (SS - 1);
          float v = acc[mt][nt][r];
          float pv = __shfl_xor(v, 1);
          float scv = tsc[s * 16 + jj];
          if (sec == 1) scv = 1.0f / scv;
          float ce = tcs[s * 16 + jj] * scv, se = tsn[s * 16 + jj] * scv;
          float o = (ln & 1) ? (v * ce + pv * se) : (v * ce - pv * se);
          if (sec == 0) o *= exp2f(l2g * (float)s);   // fold decay g^n into Q
          bf16* dst = (sec == 0) ? (bf16*)o0 : (bf16*)o1;
          dst[(size_t)grow * DD + c] = __float2bfloat16(o);
        }
      } else if (sec == 2) {
        // V transposed + fold g^(-m): vT[(b*8+h)*32 + d][s] = v(m=s,d) * g^(-s)
        const int b = grow0 >> 11, s0 = grow0 & (SS - 1);
        const int h = c >> 5, d = c & 31;
        const float nl2g = -l2g_of(h);                // positive
        float v0 = acc[mt][nt][0] * exp2f(nl2g * (float)(s0 + 0));
        float v1 = acc[mt][nt][1] * exp2f(nl2g * (float)(s0 + 1));
        float v2 = acc[mt][nt][2] * exp2f(nl2g * (float)(s0 + 2));
        float v3 = acc[mt][nt][3] * exp2f(nl2g * (float)(s0 + 3));
        uint2 pk;
        pk.x = cvtpk(v0, v1);
        pk.y = cvtpk(v2, v3);
        *(uint2*)((ushort_t*)o2 + ((size_t)(b * 8 + h) * 32 + d) * SS + s0) = pk;
      } else {
        #pragma unroll
        for (int r = 0; r < 4; ++r)
          ((float*)o3)[(size_t)(grow0 + r) * DD + c] = acc[mt][nt][r];
      }
    }
}

// ---------------- FFN mega-kernel v3: counted-vmcnt 1-deep prefetch pipeline ----------------
// BM=16 rows/block, grid MM/16=512, 4 waves; wave w owns cols [w*64, w*64+64).
// Unified 36-stage B stream (Wo 4, then per chunk FFN1 4 + FFN2 4), per-wave dbuf,
// wait vmcnt(8) per step (prev stage landed, next in flight); vmcnt(0) only at the end.
template<bool LAST>
__global__ __launch_bounds__(256, 2) void ffn_mega(
    const bf16* __restrict__ ubg, const bf16* __restrict__ wotg,
    const bf16* __restrict__ w1tg, const bf16* __restrict__ w2tg,
    const float* __restrict__ b1v, const float* __restrict__ b2v,
    const float* __restrict__ resin,
    float* __restrict__ yres, bf16* __restrict__ xn, float* __restrict__ dout,
    const float* __restrict__ l2w, const float* __restrict__ l2b,
    const float* __restrict__ lfw, const float* __restrict__ lfb,
    const float* __restrict__ l1w, const float* __restrict__ l1b)
{
  __shared__ __align__(16) ushort_t Bs[4][2][4096];    // 64 KB: per-wave dbuf 64x64
  __shared__ __align__(16) ushort_t Xs[4096];          // 8 KB: LN2 output [16][256] swizzled
  __shared__ __align__(16) ushort_t Us[4096];          // 8 KB: LN red scratch + GELU chunk

  const int bm = blockIdx.x * 16;
  const int tid = threadIdx.x;
  const int lane = tid & 63, w = tid >> 6;
  const int lg = lane >> 4, ln = lane & 15;
  const int row0 = lg * 4;
  const ushort_t* ubu  = (const ushort_t*)ubg;
  const ushort_t* wotu = (const ushort_t*)wotg;
  const ushort_t* w1tu = (const ushort_t*)w1tg;
  const ushort_t* w2tu = (const ushort_t*)w2tg;
  float* red = (float*)Us;   // [4 waves][16 rows][2], 512 B

  // hoisted register prefetches (keep mid-kernel vmcnt stream pure-B)
  float resv[4][4];
  #pragma unroll
  for (int nt = 0; nt < 4; ++nt) {
    const int gcol = w * 64 + nt * 16 + ln;
    #pragma unroll
    for (int r = 0; r < 4; ++r)
      resv[nt][r] = resin[(size_t)(bm + row0 + r) * DD + gcol];
  }
  float b1r[4][4];
  #pragma unroll
  for (int c = 0; c < 4; ++c)
    #pragma unroll
    for (int nt = 0; nt < 4; ++nt)
      b1r[c][nt] = b1v[c * 256 + w * 64 + nt * 16 + ln];
  // Wo A-fragments (16 rows) straight to registers: aw[s][kh]
  short8v aw[4][2];
  #pragma unroll
  for (int s = 0; s < 4; ++s)
    #pragma unroll
    for (int kh = 0; kh < 2; ++kh)
      aw[s][kh] = *(const short8v*)(ubu + (size_t)(bm + ln) * DD + s * 64 + kh * 32 + lg * 8);

  // wave-private B stage: rows (nbase + w*64 + r) of Wt[n][k], 64-k slice at koff
  #define STAGEBW(base, stride, nbase, koff, par) { \
    _Pragma("unroll") \
    for (int i = 0; i < 8; ++i) { \
      int slot = i * 64 + lane; int r = slot >> 3, blk = slot & 7; \
      gload_lds16((base) + (size_t)((nbase) + w * 64 + r) * (stride) + (koff) + ((blk ^ (r & 7))) * 8, &Bs[w][par][slot * 8]); \
    } }
  #define VMW8 asm volatile("s_waitcnt vmcnt(8)" ::: "memory");
  #define VMW0 asm volatile("s_waitcnt vmcnt(0)" ::: "memory");
  // one GEMM step: A from LDS array, B from Bs[w][par]
  #define FSTEP(Aarr, s, par, accv) { \
    _Pragma("unroll") \
    for (int kh = 0; kh < 2; ++kh) { \
      short8v af = *(const short8v*)&Aarr[ln * 256 + (s) * 64 + (((kh * 4 + lg) ^ (ln & 7))) * 8]; \
      _Pragma("unroll") \
      for (int nt = 0; nt < 4; ++nt) { \
        int r = nt * 16 + ln; \
        short8v bf_ = *(const short8v*)&Bs[w][par][r * 64 + (((kh * 4 + lg) ^ (r & 7))) * 8]; \
        accv[nt] = __builtin_amdgcn_mfma_f32_16x16x32_bf16(af, bf_, accv[nt], 0, 0, 0); \
      } } }

  // ---- stage stream prologue: Wo step0 -> buf0 ----
  STAGEBW(wotu, 256, 0, 0, 0)

  // ---- phase 1: Wo GEMM (stream T=0..3; no barriers, A in regs) ----
  f32x4 accw[4] = {};
  #pragma unroll
  for (int s = 0; s < 4; ++s) {
    if (s < 3) STAGEBW(wotu, 256, 0, (s + 1) * 64, (s + 1) & 1)
    else       STAGEBW(w1tu, 256, 0, 0, 0)              // T=4 (chunk0 FFN1 s0) -> buf0
    VMW8
    #pragma unroll
    for (int kh = 0; kh < 2; ++kh)
      #pragma unroll
      for (int nt = 0; nt < 4; ++nt) {
        int r = nt * 16 + ln;
        short8v bf_ = *(const short8v*)&Bs[w][s & 1][r * 64 + (((kh * 4 + lg) ^ (r & 7))) * 8];
        accw[nt] = __builtin_amdgcn_mfma_f32_16x16x32_bf16(aw[s][kh], bf_, accw[nt], 0, 0, 0);
      }
  }

  // ---- v = Wo + residual; LN2; write Xs (bf16, swizzled A-layout) ----
  float v[4][4];
  #pragma unroll
  for (int nt = 0; nt < 4; ++nt)
    #pragma unroll
    for (int r = 0; r < 4; ++r) v[nt][r] = accw[nt][r] + resv[nt][r];
  float mu[4], rsg[4];
  {
    #pragma unroll
    for (int r = 0; r < 4; ++r) {
      float s1 = 0.f, s2 = 0.f;
      #pragma unroll
      for (int nt = 0; nt < 4; ++nt) { s1 += v[nt][r]; s2 += v[nt][r] * v[nt][r]; }
      #pragma unroll
      for (int m = 8; m >= 1; m >>= 1) { s1 += __shfl_xor(s1, m); s2 += __shfl_xor(s2, m); }
      if (ln == 0) { red[(w * 16 + row0 + r) * 2] = s1; red[(w * 16 + row0 + r) * 2 + 1] = s2; }
    }
    __syncthreads();
    #pragma unroll
    for (int r = 0; r < 4; ++r) {
      float S = 0.f, S2 = 0.f;
      #pragma unroll
      for (int ww = 0; ww < 4; ++ww) { S += red[(ww * 16 + row0 + r) * 2]; S2 += red[(ww * 16 + row0 + r) * 2 + 1]; }
      float m_ = S * (1.0f / 256.0f);
      mu[r] = m_; rsg[r] = rsqrtf(S2 * (1.0f / 256.0f) - m_ * m_ + 1e-5f);
    }
  }
  #pragma unroll
  for (int nt = 0; nt < 4; ++nt) {
    const int gcol = w * 64 + nt * 16 + ln;
    const float lwv = l2w[gcol], lbv = l2b[gcol];
    const int off = nt * 16 + ln, blk = off >> 3, sub = off & 7;
    #pragma unroll
    for (int r = 0; r < 4; ++r) {
      const int row = row0 + r;
      float xv = (v[nt][r] - mu[r]) * rsg[r] * lwv + lbv;
      Xs[row * 256 + w * 64 + ((blk ^ (row & 7)) << 3) + sub] = f2b1(xv);
    }
  }
  __syncthreads();

  // ---- chunks: FFN1 (T=4+8c+s) -> GELU -> FFN2 (T=8+8c+s) ----
  f32x4 acc2[4] = {};
  #pragma unroll
  for (int c = 0; c < 4; ++c) {
    f32x4 acc1[4] = {};
    #pragma unroll
    for (int s = 0; s < 4; ++s) {
      if (s < 3) STAGEBW(w1tu, 256, c * 256, (s + 1) * 64, (s + 1) & 1)
      else       STAGEBW(w2tu, 1024, 0, c * 256, 0)     // FFN2 s0 -> buf0
      VMW8
      FSTEP(Xs, s, s & 1, acc1)
    }
    __syncthreads();   // prev chunk's FFN2 readers of Us done
    #pragma unroll
    for (int nt = 0; nt < 4; ++nt) {
      const float bb = b1r[c][nt];
      const int off = nt * 16 + ln, blk = off >> 3, sub = off & 7;
      #pragma unroll
      for (int r = 0; r < 4; ++r) {
        const int row = row0 + r;
        float t = acc1[nt][r] + bb;
        t = 0.5f * t * (1.0f + erff(t * 0.70710678118654752f));
        Us[row * 256 + w * 64 + ((blk ^ (row & 7)) << 3) + sub] = f2b1(t);
      }
    }
    __syncthreads();
    #pragma unroll
    for (int s = 0; s < 4; ++s) {
      if (s < 3)      STAGEBW(w2tu, 1024, 0, c * 256 + (s + 1) * 64, (s + 1) & 1)
      else if (c < 3) STAGEBW(w1tu, 256, (c + 1) * 256, 0, 0)
      if (c == 3 && s == 3) { VMW0 } else { VMW8 }
      FSTEP(Us, s, s & 1, acc2)
    }
  }
  __syncthreads();   // all FFN2 Us reads done before epilogue red writes

  // ---- epilogue: f = FFN2 + b2 + v; LNf; (LAST: dout) else (yres, LN1' -> xn) ----
  float f[4][4];
  #pragma unroll
  for (int nt = 0; nt < 4; ++nt) {
    const int gcol = w * 64 + nt * 16 + ln;
    const float bb = b2v[gcol];
    #pragma unroll
    for (int r = 0; r < 4; ++r) f[nt][r] = acc2[nt][r] + bb + v[nt][r];
  }
  {
    #pragma unroll
    for (int r = 0; r < 4; ++r) {
      float s1 = 0.f, s2 = 0.f;
      #pragma unroll
      for (int nt = 0; nt < 4; ++nt) { s1 += f[nt][r]; s2 += f[nt][r] * f[nt][r]; }
      #pragma unroll
      for (int m = 8; m >= 1; m >>= 1) { s1 += __shfl_xor(s1, m); s2 += __shfl_xor(s2, m); }
      if (ln == 0) { red[(w * 16 + row0 + r) * 2] = s1; red[(w * 16 + row0 + r) * 2 + 1] = s2; }
    }
    __syncthreads();
    #pragma unroll
    for (int r = 0; r < 4; ++r) {
      float S = 0.f, S2 = 0.f;
      #pragma unroll
      for (int ww = 0; ww < 4; ++ww) { S += red[(ww * 16 + row0 + r) * 2]; S2 += red[(ww * 16 + row0 + r) * 2 + 1]; }
      float m_ = S * (1.0f / 256.0f);
      mu[r] = m_; rsg[r] = rsqrtf(S2 * (1.0f / 256.0f) - m_ * m_ + 1e-5f);
    }
  }
  float u[4][4];
  #pragma unroll
  for (int nt = 0; nt < 4; ++nt) {
    const int gcol = w * 64 + nt * 16 + ln;
    const float lwv = lfw[gcol], lbv = lfb[gcol];
    #pragma unroll
    for (int r = 0; r < 4; ++r)
      u[nt][r] = (f[nt][r] - mu[r]) * rsg[r] * lwv + lbv;
  }
  if constexpr (LAST) {
    #pragma unroll
    for (int nt = 0; nt < 4; ++nt) {
      const int gcol = w * 64 + nt * 16 + ln;
      #pragma unroll
      for (int r = 0; r < 4; ++r)
        dout[(size_t)(bm + row0 + r) * DD + gcol] = u[nt][r];
    }
  } else {
    __syncthreads();
    #pragma unroll
    for (int r = 0; r < 4; ++r) {
      float s1 = 0.f, s2 = 0.f;
      #pragma unroll
      for (int nt = 0; nt < 4; ++nt) { s1 += u[nt][r]; s2 += u[nt][r] * u[nt][r]; }
      #pragma unroll
      for (int m = 8; m >= 1; m >>= 1) { s1 += __shfl_xor(s1, m); s2 += __shfl_xor(s2, m); }
      if (ln == 0) { red[(w * 16 + row0 + r) * 2] = s1; red[(w * 16 + row0 + r) * 2 + 1] = s2; }
    }
    __syncthreads();
    float mu2[4], rs2[4];
    #pragma unroll
    for (int r = 0; r < 4; ++r) {
      float S = 0.f, S2 = 0.f;
      #pragma unroll
      for (int ww = 0; ww < 4; ++ww) { S += red[(ww * 16 + row0 + r) * 2]; S2 += red[(ww * 16 + row0 + r) * 2 + 1]; }
      float m_ = S * (1.0f / 256.0f);
      mu2[r] = m_; rs2[r] = rsqrtf(S2 * (1.0f / 256.0f) - m_ * m_ + 1e-5f);
    }
    #pragma unroll
    for (int nt = 0; nt < 4; ++nt) {
      const int gcol = w * 64 + nt * 16 + ln;
      const float lwv = l1w[gcol], lbv = l1b[gcol];
      #pragma unroll
      for (int r = 0; r < 4; ++r) {
        const size_t idx = (size_t)(bm + row0 + r) * DD + gcol;
        yres[idx] = u[nt][r];
        xn[idx] = __float2bfloat16((u[nt][r] - mu2[r]) * rs2[r] * lwv + lbv);
      }
    }
  }
  #undef STAGEBW
  #undef VMW8
  #undef VMW0
  #undef FSTEP
}

// ---------------- Retention + fused GroupNorm/SiLU-gate ----------------
// Decay pre-folded: q *= g^n, vT *= g^(-m). Inner loop: raw QK -> pack -> PV.
__global__ __launch_bounds__(256) void attn_k(const bf16* __restrict__ qg, const bf16* __restrict__ kg,
    const bf16* __restrict__ vtg, const float* __restrict__ gbuf,
    const float* __restrict__ gnw, const float* __restrict__ gnb, bf16* __restrict__ ub)
{
  __shared__ __align__(16) ushort_t Kl[2][64 * 32];      // [m][k], blk ^= m&3
  __shared__ __align__(16) ushort_t Vl[2][32 * 64];      // [d][m], blk ^= d&7
  __shared__ __align__(16) unsigned int Pl[4][512];      // per wave: P^T[n=ln][64 m] bf16

  const int bh = blockIdx.x;
  const int b = bh >> 3, h = bh & (HH - 1);
  const int n0 = ((int)gridDim.y - 1 - (int)blockIdx.y) * 64;
  const int tid = threadIdx.x;
  const int w = tid >> 6, lane = tid & 63;
  const int lg = lane >> 4, ln = lane & 15;

  const size_t base = (size_t)b * SS * DD + h * HDD;
  const ushort_t* qp = (const ushort_t*)qg + base;
  const ushort_t* kp = (const ushort_t*)kg + base;
  const ushort_t* vtp = (const ushort_t*)vtg + (size_t)(b * 8 + h) * 32 * SS;

  const int n = n0 + w * 16 + ln;
  const short8v qf = *(const short8v*)(qp + (size_t)n * DD + lg * 8);

  const float l2g = l2g_of(h);                     // negative; only for window calc
  f32x4 acc0 = {0,0,0,0}, acc1 = {0,0,0,0};

  const int Wwin = (int)(20.0f / (-l2g)) + 1;
  int m_lo = 0;
  if (n0 > Wwin) m_lo = ((n0 - Wwin) >> 6) << 6;

  const int Krow = tid >> 2, Kc8 = tid & 3;
  const int Vrow = tid >> 3, Vc8 = tid & 7;

  #define STAGE(buf, m0s) { \
    gload_lds16(kp + (size_t)((m0s) + Krow) * DD + ((Kc8 ^ (Krow & 3)) * 8), &Kl[buf][tid * 8]); \
    gload_lds16(vtp + (size_t)Vrow * SS + (m0s) + ((Vc8 ^ (Vrow & 7)) * 8), &Vl[buf][tid * 8]); }

  STAGE(0, m_lo)
  asm volatile("s_waitcnt vmcnt(0)" ::: "memory");
  __builtin_amdgcn_s_barrier();

  int cur = 0;
  for (int m0 = m_lo; m0 <= n0; m0 += 64) {
    if (m0 < n0) STAGE(cur ^ 1, m0 + 64)
    const bool diag = (m0 == n0);
    __builtin_amdgcn_s_setprio(1);
    #pragma unroll
    for (int mt = 0; mt < 4; ++mt) {
      const int krow = mt * 16 + ln;
      short8v kf = *(const short8v*)&Kl[cur][krow * 32 + ((lg ^ (krow & 3)) << 3)];
      f32x4 z = {0,0,0,0};
      f32x4 pa = __builtin_amdgcn_mfma_f32_16x16x32_bf16(kf, qf, z, 0, 0, 0);
      float v0 = pa[0], v1 = pa[1], v2 = pa[2], v3 = pa[3];
      if (diag) {
        const int m = n0 + mt * 16 + lg * 4;
        v0 = (n < m)     ? 0.f : v0;
        v1 = (n < m + 1) ? 0.f : v1;
        v2 = (n < m + 2) ? 0.f : v2;
        v3 = (n < m + 3) ? 0.f : v3;
      }
      uint2 pk;
      pk.x = cvtpk(v0, v1);
      pk.y = cvtpk(v2, v3);
      const int blk = (mt * 2 + (lg >> 1)) ^ (ln & 7);
      *(uint2*)&Pl[w][ln * 32 + blk * 4 + (lg & 1) * 2] = pk;
    }
    #pragma unroll
    for (int hh = 0; hh < 2; ++hh) {
      const int pblk = (hh * 4 + lg) ^ (ln & 7);
      uint4v pw = *(const uint4v*)&Pl[w][ln * 32 + pblk * 4];
      short8v pf = __builtin_bit_cast(short8v, pw);
      #pragma unroll
      for (int dt = 0; dt < 2; ++dt) {
        const int d = dt * 16 + ln;
        short8v vf = *(const short8v*)&Vl[cur][d * 64 + (((hh * 4 + lg) ^ (d & 7)) << 3)];
        if (dt == 0) acc0 = __builtin_amdgcn_mfma_f32_16x16x32_bf16(vf, pf, acc0, 0, 0, 0);
        else         acc1 = __builtin_amdgcn_mfma_f32_16x16x32_bf16(vf, pf, acc1, 0, 0, 0);
      }
    }
    __builtin_amdgcn_s_setprio(0);
    asm volatile("s_waitcnt vmcnt(0)" ::: "memory");
    __builtin_amdgcn_s_barrier();
    cur ^= 1;
  }
  #undef STAGE

  // ---- fused GroupNorm (per head) + SiLU gate ----
  float gwv[8], gbv[8];
  #pragma unroll
  for (int dt = 0; dt < 2; ++dt) {
    f32x4 a = *(const f32x4*)&gnw[h * 32 + dt * 16 + lg * 4];
    f32x4 c = *(const f32x4*)&gnb[h * 32 + dt * 16 + lg * 4];
    #pragma unroll
    for (int r = 0; r < 4; ++r) { gwv[dt * 4 + r] = a[r]; gbv[dt * 4 + r] = c[r]; }
  }
  float s = 0.f;
  #pragma unroll
  for (int r = 0; r < 4; ++r) s += acc0[r] + acc1[r];
  s += __shfl_xor(s, 16); s += __shfl_xor(s, 32);
  const float mu = s * (1.0f / 32.0f);
  float s2 = 0.f;
  #pragma unroll
  for (int r = 0; r < 4; ++r) { float d0 = acc0[r] - mu, d1 = acc1[r] - mu; s2 += d0 * d0 + d1 * d1; }
  s2 += __shfl_xor(s2, 16); s2 += __shfl_xor(s2, 32);
  const float rs = rsqrtf(s2 * (1.0f / 32.0f) + 1e-5f);
  const size_t rowoff = ((size_t)b * SS + n) * DD + h * 32;
  #pragma unroll
  for (int dt = 0; dt < 2; ++dt) {
    f32x4 yv = dt ? acc1 : acc0;
    f32x4 gv = *(const f32x4*)&gbuf[rowoff + dt * 16 + lg * 4];
    float o0, o1, o2, o3;
    {
      float yn0 = (yv[0] - mu) * rs * gwv[dt * 4 + 0] + gbv[dt * 4 + 0];
      float yn1 = (yv[1] - mu) * rs * gwv[dt * 4 + 1] + gbv[dt * 4 + 1];
      float yn2 = (yv[2] - mu) * rs * gwv[dt * 4 + 2] + gbv[dt * 4 + 2];
      float yn3 = (yv[3] - mu) * rs * gwv[dt * 4 + 3] + gbv[dt * 4 + 3];
      o0 = gv[0] / (1.0f + expf(-gv[0])) * yn0;
      o1 = gv[1] / (1.0f + expf(-gv[1])) * yn1;
      o2 = gv[2] / (1.0f + expf(-gv[2])) * yn2;
      o3 = gv[3] / (1.0f + expf(-gv[3])) * yn3;
    }
    uint2 pk;
    pk.x = cvtpk(o0, o1);
    pk.y = cvtpk(o2, o3);
    *(uint2*)((ushort_t*)ub + rowoff + dt * 16 + lg * 4) = pk;
  }
}

extern "C" void kernel_launch(void* const* d_in, const int* in_sizes, int n_in,
                              void* d_out, int out_size, void* d_ws, size_t ws_size,
                              hipStream_t stream)
{
  const float* X    = (const float*)d_in[0];
  const float* Wq   = (const float*)d_in[1];
  const float* Wk   = (const float*)d_in[2];
  const float* Wv   = (const float*)d_in[3];
  const float* Wg   = (const float*)d_in[4];
  const float* Wo   = (const float*)d_in[5];
  const float* gnw  = (const float*)d_in[6];
  const float* gnb  = (const float*)d_in[7];
  const float* ln1w = (const float*)d_in[8];
  const float* ln1b = (const float*)d_in[9];
  const float* ln2w = (const float*)d_in[10];
  const float* ln2b = (const float*)d_in[11];
  const float* w1   = (const float*)d_in[12];
  const float* b1   = (const float*)d_in[13];
  const float* w2   = (const float*)d_in[14];
  const float* b2   = (const float*)d_in[15];
  const float* lnfw = (const float*)d_in[16];
  const float* lnfb = (const float*)d_in[17];

  // Workspace (~40 MiB)
  char* p = (char*)d_ws;
  const size_t AF  = (size_t)MM * DD * sizeof(float);  // 8 MiB
  const size_t ABF = (size_t)MM * DD * sizeof(bf16);   // 4 MiB
  bf16*  xn   = (bf16*)p;  p += ABF;
  bf16*  qb   = (bf16*)p;  p += ABF;
  bf16*  kb   = (bf16*)p;  p += ABF;
  bf16*  vT   = (bf16*)p;  p += ABF;   // [B][H][32][S], pre-scaled by g^(-m)
  bf16*  ub   = (bf16*)p;  p += ABF;
  float* gbuf = (float*)p; p += AF;
  float* yres = (float*)p; p += AF;
  bf16*  wqkvgt = (bf16*)p; p += (size_t)2 * 1024 * 256 * sizeof(bf16);
  bf16*  wot    = (bf16*)p; p += (size_t)2 * 256 * 256 * sizeof(bf16);
  bf16*  w1t    = (bf16*)p; p += (size_t)2 * 1024 * 256 * sizeof(bf16);
  bf16*  w2t    = (bf16*)p; p += (size_t)2 * 256 * 1024 * sizeof(bf16);
  float* tsn  = (float*)p; p += SS * 16 * sizeof(float);
  float* tcs  = (float*)p; p += SS * 16 * sizeof(float);
  float* tsc  = (float*)p; p += SS * 16 * sizeof(float);

  {
    WDescA da;
    for (int l = 0; l < 2; ++l) {
      da.d[l * 7 + 0] = { Wq + (size_t)l * 65536, wqkvgt + (size_t)l * 262144 + 0 * 65536, 256, 256 };
      da.d[l * 7 + 1] = { Wk + (size_t)l * 65536, wqkvgt + (size_t)l * 262144 + 1 * 65536, 256, 256 };
      da.d[l * 7 + 2] = { Wv + (size_t)l * 65536, wqkvgt + (size_t)l * 262144 + 2 * 65536, 256, 256 };
      da.d[l * 7 + 3] = { Wg + (size_t)l * 65536, wqkvgt + (size_t)l * 262144 + 3 * 65536, 256, 256 };
      da.d[l * 7 + 4] = { Wo + (size_t)l * 65536, wot + (size_t)l * 65536, 256, 256 };
      da.d[l * 7 + 5] = { w1 + (size_t)l * 262144, w1t + (size_t)l * 262144, 256, 1024 };
      da.d[l * 7 + 6] = { w2 + (size_t)l * 262144, w2t + (size_t)l * 262144, 1024, 256 };
    }
    da.tsn = tsn; da.tcs = tcs; da.tsc = tsc;
    wconv_k<<<dim3(32, 32, 15), dim3(32, 8), 0, stream>>>(da);
  }

  // layer 0 LN1 (layer 1's LN1 is fused into layer 0's mega epilogue)
  ln_k<bf16><<<dim3(MM), 256, 0, stream>>>(X, ln1w, ln1b, xn);

  for (int l = 0; l < LYR; ++l) {
    mgemm_k<64, 128, DD, E_QKVG><<<dim3(MM / 64, 1024 / 128), 256, 0, stream>>>(
        xn, wqkvgt + (size_t)l * 262144, qb, kb, vT, gbuf, tsn, tcs, tsc);
    attn_k<<<dim3(BB * HH, SS / 64), 256, 0, stream>>>(qb, kb, vT, gbuf, gnw + l * DD, gnb + l * DD, ub);
    if (l == LYR - 1) {
      ffn_mega<true><<<dim3(MM / 16), 256, 0, stream>>>(
          ub, wot + (size_t)l * 65536, w1t + (size_t)l * 262144, w2t + (size_t)l * 262144,
          b1 + l * FFD, b2 + l * DD, (l == 0) ? X : yres,
          nullptr, nullptr, (float*)d_out,
          ln2w + l * DD, ln2b + l * DD, lnfw, lnfb, nullptr, nullptr);
    } else {
      ffn_mega<false><<<dim3(MM / 16), 256, 0, stream>>>(
          ub, wot + (size_t)l * 65536, w1t + (size_t)l * 262144, w2t + (size_t)l * 262144,
          b1 + l * FFD, b2 + l * DD, (l == 0) ? X : yres,
          yres, xn, nullptr,
          ln2w + l * DD, ln2b + l * DD, lnfw, lnfb, ln1w + (l + 1) * DD, ln1b + (l + 1) * DD);
    }
  }
}

// Round 16
// 178.314 us; speedup vs baseline: 1.1249x; 1.0380x over previous
//
#include <hip/hip_runtime.h>
#include <hip/hip_bf16.h>

typedef __hip_bfloat16 bf16;
typedef unsigned short ushort_t;
typedef __attribute__((ext_vector_type(8))) short short8v;
typedef __attribute__((ext_vector_type(4))) float f32x4;
typedef __attribute__((ext_vector_type(4))) unsigned int uint4v;

// RetNet block: L=2, B=4, S=2048, D=256, H=8, HD=32, FFN*D=1024
#define LYR 2
#define BB 4
#define SS 2048
#define DD 256
#define HH 8
#define HDD 32
#define FFD 1024
#define MM (BB*SS)   // 8192 tokens

__device__ __forceinline__ unsigned int cvtpk(float lo, float hi) {
  unsigned int r;
  asm("v_cvt_pk_bf16_f32 %0, %1, %2" : "=v"(r) : "v"(lo), "v"(hi));
  return r;
}
__device__ __forceinline__ ushort_t f2b1(float x) { return (ushort_t)cvtpk(x, x); }

__device__ __forceinline__ void gload_lds16(const void* g, void* l) {
  __builtin_amdgcn_global_load_lds((const __attribute__((address_space(1))) void*)g,
                                   (__attribute__((address_space(3))) void*)l, 16, 0, 0);
}

// decay exponent: l2g(h) = log2(1 - exp(log(1/32) + h*(log(1/512)-log(1/32))/7))  (negative)
__device__ __forceinline__ float l2g_of(int h) {
  return log2f(1.0f - expf(-3.4657359028f - 0.3960841187f * (float)h));
}

// ---------------- weight transpose+convert + xPos tables (z==14) ----------------
struct WDesc { const float* src; bf16* dst; int K; int N; };
struct WDescA { WDesc d[14]; float* tsn; float* tcs; float* tsc; };
__global__ __launch_bounds__(256) void wconv_k(WDescA da) {
  if (blockIdx.z == 14) {
    int i = (blockIdx.y * 32 + blockIdx.x) * 256 + threadIdx.y * 32 + threadIdx.x;
    if (i >= SS * 16) return;
    int s = i >> 4, j = i & 15;
    float sv = (2.0f * (float)j + 0.4f * (float)HDD) / (1.4f * (float)HDD);
    da.tsc[i] = powf(sv, (float)s * (1.0f / 512.0f));
    float inv_freq = powf(10000.0f, -(float)j * (1.0f / 16.0f));
    float ang = (float)s * inv_freq;
    da.tsn[i] = sinf(ang);
    da.tcs[i] = cosf(ang);
    return;
  }
  WDesc dd = da.d[blockIdx.z];
  int n0 = blockIdx.x * 32, k0 = blockIdx.y * 32;
  if (n0 >= dd.N || k0 >= dd.K) return;
  __shared__ float t[32][33];
  int tx = threadIdx.x, ty = threadIdx.y;   // 32 x 8
  #pragma unroll
  for (int i = 0; i < 32; i += 8) t[ty + i][tx] = dd.src[(size_t)(k0 + ty + i) * dd.N + n0 + tx];
  __syncthreads();
  #pragma unroll
  for (int i = 0; i < 32; i += 8) dd.dst[(size_t)(n0 + ty + i) * dd.K + k0 + tx] = __float2bfloat16(t[tx][ty + i]);
}

// ---------------- LayerNorm over D=256 (one block per row), f32 in, OT out ----------------
template<typename OT>
__global__ __launch_bounds__(256) void ln_k(const float* __restrict__ in, const float* __restrict__ w,
    const float* __restrict__ b, OT* __restrict__ out)
{
  int row = blockIdx.x, t = threadIdx.x;
  float v = in[(size_t)row * DD + t];
  __shared__ float red[4];
  float s = v;
  #pragma unroll
  for (int m = 32; m >= 1; m >>= 1) s += __shfl_xor(s, m);
  if ((t & 63) == 0) red[t >> 6] = s;
  __syncthreads();
  float mu = (red[0] + red[1] + red[2] + red[3]) * (1.0f / 256.0f);
  float d = v - mu;
  float s2 = d * d;
  #pragma unroll
  for (int m = 32; m >= 1; m >>= 1) s2 += __shfl_xor(s2, m);
  __syncthreads();
  if ((t & 63) == 0) red[t >> 6] = s2;
  __syncthreads();
  float var = (red[0] + red[1] + red[2] + red[3]) * (1.0f / 256.0f);
  float o = d * rsqrtf(var + 1e-5f) * w[t] + b[t];
  if constexpr (sizeof(OT) == 2) out[(size_t)row * DD + t] = __float2bfloat16(o);
  else                           out[(size_t)row * DD + t] = o;
}

#define STAGEG(buf, k0s) { \
    _Pragma("unroll") \
    for (int i = 0; i < BM / 32; ++i) { \
      int slot = i * 256 + tid; int row = slot >> 3, blk = slot & 7; \
      gload_lds16(Au + (size_t)(bm + row) * K + (k0s) + ((blk ^ (row & 7))) * 8, &Al[buf][slot * 8]); \
    } \
    _Pragma("unroll") \
    for (int i = 0; i < BN / 32; ++i) { \
      int slot = i * 256 + tid; int row = slot >> 3, blk = slot & 7; \
      gload_lds16(Bu + (size_t)(bn + row) * K + (k0s) + ((blk ^ (row & 7))) * 8, &Bl[buf][slot * 8]); \
    } }

// ---------------- bf16 MFMA GEMM (QKVG projection), double-buffered ----------------
enum { E_QKVG = 0 };

template<int BM, int BN, int K, int EPI>
__global__ __launch_bounds__(256) void mgemm_k(const bf16* __restrict__ Ag, const bf16* __restrict__ Wt,
    void* o0, void* o1, void* o2, void* o3,
    const float* __restrict__ tsn, const float* __restrict__ tcs, const float* __restrict__ tsc)
{
  constexpr int MT = BM / 32, NT = BN / 32;
  constexpr int WMH = BM / 2, WNH = BN / 2;
  __shared__ __align__(16) ushort_t Al[2][BM * 64];
  __shared__ __align__(16) ushort_t Bl[2][BN * 64];
  const int bm = blockIdx.x * BM;
  const int bn = blockIdx.y * BN;
  const int tid = threadIdx.x;
  const int lane = tid & 63, w = tid >> 6;
  const int lg = lane >> 4, ln = lane & 15;
  const int wr = w >> 1, wc = w & 1;
  const ushort_t* Au = (const ushort_t*)Ag;
  const ushort_t* Bu = (const ushort_t*)Wt;
  f32x4 acc[MT][NT] = {};

  STAGEG(0, 0)
  asm volatile("s_waitcnt vmcnt(0)" ::: "memory");
  __builtin_amdgcn_s_barrier();

  int cur = 0;
  for (int k0 = 0; k0 < K; k0 += 64) {
    if (k0 + 64 < K) STAGEG(cur ^ 1, k0 + 64)
    #pragma unroll
    for (int kh = 0; kh < 2; ++kh) {
      short8v af[MT], bfr[NT];
      #pragma unroll
      for (int mt = 0; mt < MT; ++mt) {
        int row = wr * WMH + mt * 16 + ln;
        af[mt] = *(const short8v*)&Al[cur][row * 64 + (((kh * 4 + lg) ^ (row & 7))) * 8];
      }
      #pragma unroll
      for (int nt = 0; nt < NT; ++nt) {
        int row = wc * WNH + nt * 16 + ln;
        bfr[nt] = *(const short8v*)&Bl[cur][row * 64 + (((kh * 4 + lg) ^ (row & 7))) * 8];
      }
      #pragma unroll
      for (int mt = 0; mt < MT; ++mt)
        #pragma unroll
        for (int nt = 0; nt < NT; ++nt)
          acc[mt][nt] = __builtin_amdgcn_mfma_f32_16x16x32_bf16(af[mt], bfr[nt], acc[mt][nt], 0, 0, 0);
    }
    asm volatile("s_waitcnt vmcnt(0)" ::: "memory");
    __builtin_amdgcn_s_barrier();
    cur ^= 1;
  }

  #pragma unroll
  for (int mt = 0; mt < MT; ++mt)
    #pragma unroll
    for (int nt = 0; nt < NT; ++nt) {
      const int colbase = bn + wc * WNH + nt * 16;
      const int sec = colbase >> 8;          // 0=Q 1=K 2=V 3=G (uniform per block)
      const int c = (colbase & 255) + ln;
      const int grow0 = bm + wr * WMH + mt * 16 + lg * 4;
      if (sec <= 1) {
        const int jj = (c & 31) >> 1;
        const float l2g = l2g_of(c >> 5);
        #pragma unroll
        for (int r = 0; r < 4; ++r) {
          const int grow = grow0 + r;
          const int s = grow & (SS - 1);
          float v = acc[mt][nt][r];
          float pv = __shfl_xor(v, 1);
          float scv = tsc[s * 16 + jj];
          if (sec == 1) scv = 1.0f / scv;
          float ce = tcs[s * 16 + jj] * scv, se = tsn[s * 16 + jj] * scv;
          float o = (ln & 1) ? (v * ce + pv * se) : (v * ce - pv * se);
          if (sec == 0) o *= exp2f(l2g * (float)s);   // fold decay g^n into Q
          bf16* dst = (sec == 0) ? (bf16*)o0 : (bf16*)o1;
          dst[(size_t)grow * DD + c] = __float2bfloat16(o);
        }
      } else if (sec == 2) {
        // V transposed + fold g^(-m): vT[(b*8+h)*32 + d][s] = v(m=s,d) * g^(-s)
        const int b = grow0 >> 11, s0 = grow0 & (SS - 1);
        const int h = c >> 5, d = c & 31;
        const float nl2g = -l2g_of(h);                // positive
        float v0 = acc[mt][nt][0] * exp2f(nl2g * (float)(s0 + 0));
        float v1 = acc[mt][nt][1] * exp2f(nl2g * (float)(s0 + 1));
        float v2 = acc[mt][nt][2] * exp2f(nl2g * (float)(s0 + 2));
        float v3 = acc[mt][nt][3] * exp2f(nl2g * (float)(s0 + 3));
        uint2 pk;
        pk.x = cvtpk(v0, v1);
        pk.y = cvtpk(v2, v3);
        *(uint2*)((ushort_t*)o2 + ((size_t)(b * 8 + h) * 32 + d) * SS + s0) = pk;
      } else {
        #pragma unroll
        for (int r = 0; r < 4; ++r)
          ((float*)o3)[(size_t)(grow0 + r) * DD + c] = acc[mt][nt][r];
      }
    }
}

// ---------------- FFN mega-kernel v4: BM=32, 8 waves, depth-2 counted prefetch ----------------
// grid MM/32=256 (1 block/CU), 512 threads; wave w owns cols [w*32, w*32+32) of each 256-seg.
// 36-stage B stream (Wo 4, per chunk FFN1 4 + FFN2 4), per-wave triple buffer (4 loads/stage),
// vmcnt(8)=2 stages in flight; vmcnt(4)/(0) at tail. LDS 128KB.
template<bool LAST>
__global__ __launch_bounds__(512, 1) void ffn_mega(
    const bf16* __restrict__ ubg, const bf16* __restrict__ wotg,
    const bf16* __restrict__ w1tg, const bf16* __restrict__ w2tg,
    const float* __restrict__ b1v, const float* __restrict__ b2v,
    const float* __restrict__ resin,
    float* __restrict__ yres, bf16* __restrict__ xn, float* __restrict__ dout,
    const float* __restrict__ l2w, const float* __restrict__ l2b,
    const float* __restrict__ lfw, const float* __restrict__ lfb,
    const float* __restrict__ l1w, const float* __restrict__ l1b)
{
  __shared__ __align__(16) ushort_t Bs[8][3][2048];    // 96 KB: per-wave 32n x 64k, 3 bufs
  __shared__ __align__(16) ushort_t Xs[8192];          // 16 KB: A [32][256] swizzled (ub, then LN2)
  __shared__ __align__(16) ushort_t Us[8192];          // 16 KB: LN red scratch + GELU chunk

  const int bm = blockIdx.x * 32;
  const int tid = threadIdx.x;
  const int lane = tid & 63, w = tid >> 6;
  const int lg = lane >> 4, ln = lane & 15;
  const int row0 = lg * 4;
  const ushort_t* ubu  = (const ushort_t*)ubg;
  const ushort_t* wotu = (const ushort_t*)wotg;
  const ushort_t* w1tu = (const ushort_t*)w1tg;
  const ushort_t* w2tu = (const ushort_t*)w2tg;
  float* red = (float*)Us;   // [8 waves][32 rows][2], 2 KB

  // hoisted register prefetches (keep mid-kernel vmcnt stream pure-B)
  float resv[2][2][4];
  #pragma unroll
  for (int mt = 0; mt < 2; ++mt)
    #pragma unroll
    for (int nt = 0; nt < 2; ++nt) {
      const int gcol = w * 32 + nt * 16 + ln;
      #pragma unroll
      for (int r = 0; r < 4; ++r)
        resv[mt][nt][r] = resin[(size_t)(bm + mt * 16 + row0 + r) * DD + gcol];
    }
  float b1r[4][2];
  #pragma unroll
  for (int c = 0; c < 4; ++c)
    #pragma unroll
    for (int nt = 0; nt < 2; ++nt)
      b1r[c][nt] = b1v[c * 256 + w * 32 + nt * 16 + ln];
  float b2r[2], l2wr[2], l2br[2], lfwr[2], lfbr[2], l1wr[2], l1br[2];
  #pragma unroll
  for (int nt = 0; nt < 2; ++nt) {
    const int gcol = w * 32 + nt * 16 + ln;
    b2r[nt] = b2v[gcol];
    l2wr[nt] = l2w[gcol]; l2br[nt] = l2b[gcol];
    lfwr[nt] = lfw[gcol]; lfbr[nt] = lfb[gcol];
    if constexpr (!LAST) { l1wr[nt] = l1w[gcol]; l1br[nt] = l1b[gcol]; }
  }

  // wave-private B stage: rows (nbase + w*32 + r) of Wt, 64-k slice at koff (4 insts)
  #define STAGEBW(base, stride, nbase, koff, par) { \
    _Pragma("unroll") \
    for (int i = 0; i < 4; ++i) { \
      int slot = i * 64 + lane; int r = slot >> 3, blk = slot & 7; \
      gload_lds16((base) + (size_t)((nbase) + w * 32 + r) * (stride) + (koff) + ((blk ^ (r & 7))) * 8, &Bs[w][par][slot * 8]); \
    } }
  // cooperative A stage: ub[bm..bm+32][256] -> Xs swizzled (2 insts/lane, 512 threads)
  #define STAGEA { \
    _Pragma("unroll") \
    for (int i = 0; i < 2; ++i) { \
      int slot = i * 512 + tid; int row = slot >> 5, b5 = slot & 31; \
      int sb = (b5 & ~7) | ((b5 & 7) ^ (row & 7)); \
      gload_lds16(ubu + (size_t)(bm + row) * DD + sb * 8, &Xs[slot * 8]); \
    } }
  #define VMW8 asm volatile("s_waitcnt vmcnt(8)" ::: "memory");
  #define VMW4 asm volatile("s_waitcnt vmcnt(4)" ::: "memory");
  #define VMW0 asm volatile("s_waitcnt vmcnt(0)" ::: "memory");
  // one GEMM step: A[32][256] swizzled from Aarr, B from Bs[w][par]; acc[2][2]
  #define FSTEP(Aarr, s, par, accv) { \
    _Pragma("unroll") \
    for (int kh = 0; kh < 2; ++kh) { \
      short8v af[2], bfr[2]; \
      _Pragma("unroll") \
      for (int mt = 0; mt < 2; ++mt) { \
        int ra = mt * 16 + ln; \
        af[mt] = *(const short8v*)&Aarr[ra * 256 + (s) * 64 + (((kh * 4 + lg) ^ (ra & 7))) * 8]; \
      } \
      _Pragma("unroll") \
      for (int nt = 0; nt < 2; ++nt) { \
        int rb = nt * 16 + ln; \
        bfr[nt] = *(const short8v*)&Bs[w][par][rb * 64 + (((kh * 4 + lg) ^ (rb & 7))) * 8]; \
      } \
      _Pragma("unroll") \
      for (int mt = 0; mt < 2; ++mt) \
        _Pragma("unroll") \
        for (int nt = 0; nt < 2; ++nt) \
          accv[mt][nt] = __builtin_amdgcn_mfma_f32_16x16x32_bf16(af[mt], bfr[nt], accv[mt][nt], 0, 0, 0); \
    } }
  // swizzled LDS write of one value at (row, col) in a [32][256] A-layout buffer
  #define SWZST(buf, row, col, val) { \
    int g_ = (col) >> 3, sub_ = (col) & 7; \
    int gs_ = (g_ & ~7) | ((g_ & 7) ^ ((row) & 7)); \
    buf[(row) * 256 + gs_ * 8 + sub_] = f2b1(val); }

  // ---- prologue: A + stages T0,T1 ----
  STAGEA
  STAGEBW(wotu, 256, 0, 0, 0)
  STAGEBW(wotu, 256, 0, 64, 1)
  VMW4                          // A + T0 landed (T1 in flight)
  __builtin_amdgcn_s_barrier();

  // ---- phase 1: Wo GEMM (T=0..3) ----
  f32x4 accw[2][2] = {};
  #pragma unroll
  for (int s = 0; s < 4; ++s) {
    if (s < 2) STAGEBW(wotu, 256, 0, (s + 2) * 64, (s + 2) % 3)
    else       STAGEBW(w1tu, 256, 0, (s - 2) * 64, (s + 2) % 3)   // T4,T5 = FFN1 c0 s0,s1
    VMW8
    FSTEP(Xs, s, s % 3, accw)
  }

  // ---- v = Wo + residual; LN2; overwrite Xs with LN2 out ----
  float v[2][2][4];
  #pragma unroll
  for (int mt = 0; mt < 2; ++mt)
    #pragma unroll
    for (int nt = 0; nt < 2; ++nt)
      #pragma unroll
      for (int r = 0; r < 4; ++r) v[mt][nt][r] = accw[mt][nt][r] + resv[mt][nt][r];
  float mu[2][4], rsg[2][4];
  {
    #pragma unroll
    for (int mt = 0; mt < 2; ++mt)
      #pragma unroll
      for (int r = 0; r < 4; ++r) {
        float s1 = 0.f, s2 = 0.f;
        #pragma unroll
        for (int nt = 0; nt < 2; ++nt) { s1 += v[mt][nt][r]; s2 += v[mt][nt][r] * v[mt][nt][r]; }
        #pragma unroll
        for (int m = 8; m >= 1; m >>= 1) { s1 += __shfl_xor(s1, m); s2 += __shfl_xor(s2, m); }
        if (ln == 0) { red[(w * 32 + mt * 16 + row0 + r) * 2] = s1; red[(w * 32 + mt * 16 + row0 + r) * 2 + 1] = s2; }
      }
    __syncthreads();
    #pragma unroll
    for (int mt = 0; mt < 2; ++mt)
      #pragma unroll
      for (int r = 0; r < 4; ++r) {
        float S = 0.f, S2 = 0.f;
        #pragma unroll
        for (int ww = 0; ww < 8; ++ww) {
          S  += red[(ww * 32 + mt * 16 + row0 + r) * 2];
          S2 += red[(ww * 32 + mt * 16 + row0 + r) * 2 + 1];
        }
        float m_ = S * (1.0f / 256.0f);
        mu[mt][r] = m_; rsg[mt][r] = rsqrtf(S2 * (1.0f / 256.0f) - m_ * m_ + 1e-5f);
      }
  }
  __syncthreads();   // all Xs(A) reads + red reads done before Xs overwrite
  #pragma unroll
  for (int mt = 0; mt < 2; ++mt)
    #pragma unroll
    for (int nt = 0; nt < 2; ++nt) {
      const int col = w * 32 + nt * 16 + ln;
      #pragma unroll
      for (int r = 0; r < 4; ++r) {
        const int row = mt * 16 + row0 + r;
        float xv = (v[mt][nt][r] - mu[mt][r]) * rsg[mt][r] * l2wr[nt] + l2br[nt];
        SWZST(Xs, row, col, xv)
      }
    }
  __syncthreads();

  // ---- chunks: FFN1 (T=4+8c+s) -> GELU -> FFN2 (T=8+8c+s) ----
  f32x4 acc2[2][2] = {};
  #pragma unroll
  for (int c = 0; c < 4; ++c) {
    f32x4 acc1[2][2] = {};
    #pragma unroll
    for (int s = 0; s < 4; ++s) {
      if (s < 2) STAGEBW(w1tu, 256, c * 256, (s + 2) * 64, (6 + 8 * c + s) % 3)
      else       STAGEBW(w2tu, 1024, 0, c * 256 + (s - 2) * 64, (6 + 8 * c + s) % 3)
      VMW8
      FSTEP(Xs, s, (4 + 8 * c + s) % 3, acc1)
    }
    __syncthreads();   // prev chunk's FFN2 Us readers done
    #pragma unroll
    for (int mt = 0; mt < 2; ++mt)
      #pragma unroll
      for (int nt = 0; nt < 2; ++nt) {
        const int col = w * 32 + nt * 16 + ln;
        #pragma unroll
        for (int r = 0; r < 4; ++r) {
          const int row = mt * 16 + row0 + r;
          float t = acc1[mt][nt][r] + b1r[c][nt];
          t = 0.5f * t * (1.0f + erff(t * 0.70710678118654752f));
          SWZST(Us, row, col, t)
        }
      }
    __syncthreads();
    #pragma unroll
    for (int s = 0; s < 4; ++s) {
      if (s < 2)      STAGEBW(w2tu, 1024, 0, c * 256 + (s + 2) * 64, (10 + 8 * c + s) % 3)
      else if (c < 3) STAGEBW(w1tu, 256, (c + 1) * 256, (s - 2) * 64, (10 + 8 * c + s) % 3)
      if (c == 3 && s == 2) { VMW4 }
      else if (c == 3 && s == 3) { VMW0 }
      else { VMW8 }
      FSTEP(Us, s, (8 + 8 * c + s) % 3, acc2)
    }
  }
  __syncthreads();   // all FFN2 Us reads done before epilogue red writes

  // ---- epilogue: f = FFN2 + b2 + v; LNf; (LAST: dout) else (yres, LN1' -> xn) ----
  float f[2][2][4];
  #pragma unroll
  for (int mt = 0; mt < 2; ++mt)
    #pragma unroll
    for (int nt = 0; nt < 2; ++nt)
      #pragma unroll
      for (int r = 0; r < 4; ++r)
        f[mt][nt][r] = acc2[mt][nt][r] + b2r[nt] + v[mt][nt][r];
  {
    #pragma unroll
    for (int mt = 0; mt < 2; ++mt)
      #pragma unroll
      for (int r = 0; r < 4; ++r) {
        float s1 = 0.f, s2 = 0.f;
        #pragma unroll
        for (int nt = 0; nt < 2; ++nt) { s1 += f[mt][nt][r]; s2 += f[mt][nt][r] * f[mt][nt][r]; }
        #pragma unroll
        for (int m = 8; m >= 1; m >>= 1) { s1 += __shfl_xor(s1, m); s2 += __shfl_xor(s2, m); }
        if (ln == 0) { red[(w * 32 + mt * 16 + row0 + r) * 2] = s1; red[(w * 32 + mt * 16 + row0 + r) * 2 + 1] = s2; }
      }
    __syncthreads();
    #pragma unroll
    for (int mt = 0; mt < 2; ++mt)
      #pragma unroll
      for (int r = 0; r < 4; ++r) {
        float S = 0.f, S2 = 0.f;
        #pragma unroll
        for (int ww = 0; ww < 8; ++ww) {
          S  += red[(ww * 32 + mt * 16 + row0 + r) * 2];
          S2 += red[(ww * 32 + mt * 16 + row0 + r) * 2 + 1];
        }
        float m_ = S * (1.0f / 256.0f);
        mu[mt][r] = m_; rsg[mt][r] = rsqrtf(S2 * (1.0f / 256.0f) - m_ * m_ + 1e-5f);
      }
  }
  float u[2][2][4];
  #pragma unroll
  for (int mt = 0; mt < 2; ++mt)
    #pragma unroll
    for (int nt = 0; nt < 2; ++nt)
      #pragma unroll
      for (int r = 0; r < 4; ++r)
        u[mt][nt][r] = (f[mt][nt][r] - mu[mt][r]) * rsg[mt][r] * lfwr[nt] + lfbr[nt];
  if constexpr (LAST) {
    #pragma unroll
    for (int mt = 0; mt < 2; ++mt)
      #pragma unroll
      for (int nt = 0; nt < 2; ++nt) {
        const int gcol = w * 32 + nt * 16 + ln;
        #pragma unroll
        for (int r = 0; r < 4; ++r)
          dout[(size_t)(bm + mt * 16 + row0 + r) * DD + gcol] = u[mt][nt][r];
      }
  } else {
    __syncthreads();
    #pragma unroll
    for (int mt = 0; mt < 2; ++mt)
      #pragma unroll
      for (int r = 0; r < 4; ++r) {
        float s1 = 0.f, s2 = 0.f;
        #pragma unroll
        for (int nt = 0; nt < 2; ++nt) { s1 += u[mt][nt][r]; s2 += u[mt][nt][r] * u[mt][nt][r]; }
        #pragma unroll
        for (int m = 8; m >= 1; m >>= 1) { s1 += __shfl_xor(s1, m); s2 += __shfl_xor(s2, m); }
        if (ln == 0) { red[(w * 32 + mt * 16 + row0 + r) * 2] = s1; red[(w * 32 + mt * 16 + row0 + r) * 2 + 1] = s2; }
      }
    __syncthreads();
    float mu2[2][4], rs2[2][4];
    #pragma unroll
    for (int mt = 0; mt < 2; ++mt)
      #pragma unroll
      for (int r = 0; r < 4; ++r) {
        float S = 0.f, S2 = 0.f;
        #pragma unroll
        for (int ww = 0; ww < 8; ++ww) {
          S  += red[(ww * 32 + mt * 16 + row0 + r) * 2];
          S2 += red[(ww * 32 + mt * 16 + row0 + r) * 2 + 1];
        }
        float m_ = S * (1.0f / 256.0f);
        mu2[mt][r] = m_; rs2[mt][r] = rsqrtf(S2 * (1.0f / 256.0f) - m_ * m_ + 1e-5f);
      }
    #pragma unroll
    for (int mt = 0; mt < 2; ++mt)
      #pragma unroll
      for (int nt = 0; nt < 2; ++nt) {
        const int gcol = w * 32 + nt * 16 + ln;
        #pragma unroll
        for (int r = 0; r < 4; ++r) {
          const size_t idx = (size_t)(bm + mt * 16 + row0 + r) * DD + gcol;
          yres[idx] = u[mt][nt][r];
          xn[idx] = __float2bfloat16((u[mt][nt][r] - mu2[mt][r]) * rs2[mt][r] * l1wr[nt] + l1br[nt]);
        }
      }
  }
  #undef STAGEBW
  #undef STAGEA
  #undef VMW8
  #undef VMW4
  #undef VMW0
  #undef FSTEP
  #undef SWZST
}

// ---------------- Retention + fused GroupNorm/SiLU-gate ----------------
// Decay pre-folded: q *= g^n, vT *= g^(-m). Inner loop: raw QK -> pack -> PV.
__global__ __launch_bounds__(256) void attn_k(const bf16* __restrict__ qg, const bf16* __restrict__ kg,
    const bf16* __restrict__ vtg, const float* __restrict__ gbuf,
    const float* __restrict__ gnw, const float* __restrict__ gnb, bf16* __restrict__ ub)
{
  __shared__ __align__(16) ushort_t Kl[2][64 * 32];      // [m][k], blk ^= m&3
  __shared__ __align__(16) ushort_t Vl[2][32 * 64];      // [d][m], blk ^= d&7
  __shared__ __align__(16) unsigned int Pl[4][512];      // per wave: P^T[n=ln][64 m] bf16

  const int bh = blockIdx.x;
  const int b = bh >> 3, h = bh & (HH - 1);
  const int n0 = ((int)gridDim.y - 1 - (int)blockIdx.y) * 64;
  const int tid = threadIdx.x;
  const int w = tid >> 6, lane = tid & 63;
  const int lg = lane >> 4, ln = lane & 15;

  const size_t base = (size_t)b * SS * DD + h * HDD;
  const ushort_t* qp = (const ushort_t*)qg + base;
  const ushort_t* kp = (const ushort_t*)kg + base;
  const ushort_t* vtp = (const ushort_t*)vtg + (size_t)(b * 8 + h) * 32 * SS;

  const int n = n0 + w * 16 + ln;
  const short8v qf = *(const short8v*)(qp + (size_t)n * DD + lg * 8);

  const float l2g = l2g_of(h);                     // negative; only for window calc
  f32x4 acc0 = {0,0,0,0}, acc1 = {0,0,0,0};

  const int Wwin = (int)(20.0f / (-l2g)) + 1;
  int m_lo = 0;
  if (n0 > Wwin) m_lo = ((n0 - Wwin) >> 6) << 6;

  const int Krow = tid >> 2, Kc8 = tid & 3;
  const int Vrow = tid >> 3, Vc8 = tid & 7;

  #define STAGE(buf, m0s) { \
    gload_lds16(kp + (size_t)((m0s) + Krow) * DD + ((Kc8 ^ (Krow & 3)) * 8), &Kl[buf][tid * 8]); \
    gload_lds16(vtp + (size_t)Vrow * SS + (m0s) + ((Vc8 ^ (Vrow & 7)) * 8), &Vl[buf][tid * 8]); }

  STAGE(0, m_lo)
  asm volatile("s_waitcnt vmcnt(0)" ::: "memory");
  __builtin_amdgcn_s_barrier();

  int cur = 0;
  for (int m0 = m_lo; m0 <= n0; m0 += 64) {
    if (m0 < n0) STAGE(cur ^ 1, m0 + 64)
    const bool diag = (m0 == n0);
    __builtin_amdgcn_s_setprio(1);
    #pragma unroll
    for (int mt = 0; mt < 4; ++mt) {
      const int krow = mt * 16 + ln;
      short8v kf = *(const short8v*)&Kl[cur][krow * 32 + ((lg ^ (krow & 3)) << 3)];
      f32x4 z = {0,0,0,0};
      f32x4 pa = __builtin_amdgcn_mfma_f32_16x16x32_bf16(kf, qf, z, 0, 0, 0);
      float v0 = pa[0], v1 = pa[1], v2 = pa[2], v3 = pa[3];
      if (diag) {
        const int m = n0 + mt * 16 + lg * 4;
        v0 = (n < m)     ? 0.f : v0;
        v1 = (n < m + 1) ? 0.f : v1;
        v2 = (n < m + 2) ? 0.f : v2;
        v3 = (n < m + 3) ? 0.f : v3;
      }
      uint2 pk;
      pk.x = cvtpk(v0, v1);
      pk.y = cvtpk(v2, v3);
      const int blk = (mt * 2 + (lg >> 1)) ^ (ln & 7);
      *(uint2*)&Pl[w][ln * 32 + blk * 4 + (lg & 1) * 2] = pk;
    }
    #pragma unroll
    for (int hh = 0; hh < 2; ++hh) {
      const int pblk = (hh * 4 + lg) ^ (ln & 7);
      uint4v pw = *(const uint4v*)&Pl[w][ln * 32 + pblk * 4];
      short8v pf = __builtin_bit_cast(short8v, pw);
      #pragma unroll
      for (int dt = 0; dt < 2; ++dt) {
        const int d = dt * 16 + ln;
        short8v vf = *(const short8v*)&Vl[cur][d * 64 + (((hh * 4 + lg) ^ (d & 7)) << 3)];
        if (dt == 0) acc0 = __builtin_amdgcn_mfma_f32_16x16x32_bf16(vf, pf, acc0, 0, 0, 0);
        else         acc1 = __builtin_amdgcn_mfma_f32_16x16x32_bf16(vf, pf, acc1, 0, 0, 0);
      }
    }
    __builtin_amdgcn_s_setprio(0);
    asm volatile("s_waitcnt vmcnt(0)" ::: "memory");
    __builtin_amdgcn_s_barrier();
    cur ^= 1;
  }
  #undef STAGE

  // ---- fused GroupNorm (per head) + SiLU gate ----
  float gwv[8], gbv[8];
  #pragma unroll
  for (int dt = 0; dt < 2; ++dt) {
    f32x4 a = *(const f32x4*)&gnw[h * 32 + dt * 16 + lg * 4];
    f32x4 c = *(const f32x4*)&gnb[h * 32 + dt * 16 + lg * 4];
    #pragma unroll
    for (int r = 0; r < 4; ++r) { gwv[dt * 4 + r] = a[r]; gbv[dt * 4 + r] = c[r]; }
  }
  float s = 0.f;
  #pragma unroll
  for (int r = 0; r < 4; ++r) s += acc0[r] + acc1[r];
  s += __shfl_xor(s, 16); s += __shfl_xor(s, 32);
  const float mu = s * (1.0f / 32.0f);
  float s2 = 0.f;
  #pragma unroll
  for (int r = 0; r < 4; ++r) { float d0 = acc0[r] - mu, d1 = acc1[r] - mu; s2 += d0 * d0 + d1 * d1; }
  s2 += __shfl_xor(s2, 16); s2 += __shfl_xor(s2, 32);
  const float rs = rsqrtf(s2 * (1.0f / 32.0f) + 1e-5f);
  const size_t rowoff = ((size_t)b * SS + n) * DD + h * 32;
  #pragma unroll
  for (int dt = 0; dt < 2; ++dt) {
    f32x4 yv = dt ? acc1 : acc0;
    f32x4 gv = *(const f32x4*)&gbuf[rowoff + dt * 16 + lg * 4];
    float o0, o1, o2, o3;
    {
      float yn0 = (yv[0] - mu) * rs * gwv[dt * 4 + 0] + gbv[dt * 4 + 0];
      float yn1 = (yv[1] - mu) * rs * gwv[dt * 4 + 1] + gbv[dt * 4 + 1];
      float yn2 = (yv[2] - mu) * rs * gwv[dt * 4 + 2] + gbv[dt * 4 + 2];
      float yn3 = (yv[3] - mu) * rs * gwv[dt * 4 + 3] + gbv[dt * 4 + 3];
      o0 = gv[0] / (1.0f + expf(-gv[0])) * yn0;
      o1 = gv[1] / (1.0f + expf(-gv[1])) * yn1;
      o2 = gv[2] / (1.0f + expf(-gv[2])) * yn2;
      o3 = gv[3] / (1.0f + expf(-gv[3])) * yn3;
    }
    uint2 pk;
    pk.x = cvtpk(o0, o1);
    pk.y = cvtpk(o2, o3);
    *(uint2*)((ushort_t*)ub + rowoff + dt * 16 + lg * 4) = pk;
  }
}

extern "C" void kernel_launch(void* const* d_in, const int* in_sizes, int n_in,
                              void* d_out, int out_size, void* d_ws, size_t ws_size,
                              hipStream_t stream)
{
  const float* X    = (const float*)d_in[0];
  const float* Wq   = (const float*)d_in[1];
  const float* Wk   = (const float*)d_in[2];
  const float* Wv   = (const float*)d_in[3];
  const float* Wg   = (const float*)d_in[4];
  const float* Wo   = (const float*)d_in[5];
  const float* gnw  = (const float*)d_in[6];
  const float* gnb  = (const float*)d_in[7];
  const float* ln1w = (const float*)d_in[8];
  const float* ln1b = (const float*)d_in[9];
  const float* ln2w = (const float*)d_in[10];
  const float* ln2b = (const float*)d_in[11];
  const float* w1   = (const float*)d_in[12];
  const float* b1   = (const float*)d_in[13];
  const float* w2   = (const float*)d_in[14];
  const float* b2   = (const float*)d_in[15];
  const float* lnfw = (const float*)d_in[16];
  const float* lnfb = (const float*)d_in[17];

  // Workspace (~40 MiB)
  char* p = (char*)d_ws;
  const size_t AF  = (size_t)MM * DD * sizeof(float);  // 8 MiB
  const size_t ABF = (size_t)MM * DD * sizeof(bf16);   // 4 MiB
  bf16*  xn   = (bf16*)p;  p += ABF;
  bf16*  qb   = (bf16*)p;  p += ABF;
  bf16*  kb   = (bf16*)p;  p += ABF;
  bf16*  vT   = (bf16*)p;  p += ABF;   // [B][H][32][S], pre-scaled by g^(-m)
  bf16*  ub   = (bf16*)p;  p += ABF;
  float* gbuf = (float*)p; p += AF;
  float* yres = (float*)p; p += AF;
  bf16*  wqkvgt = (bf16*)p; p += (size_t)2 * 1024 * 256 * sizeof(bf16);
  bf16*  wot    = (bf16*)p; p += (size_t)2 * 256 * 256 * sizeof(bf16);
  bf16*  w1t    = (bf16*)p; p += (size_t)2 * 1024 * 256 * sizeof(bf16);
  bf16*  w2t    = (bf16*)p; p += (size_t)2 * 256 * 1024 * sizeof(bf16);
  float* tsn  = (float*)p; p += SS * 16 * sizeof(float);
  float* tcs  = (float*)p; p += SS * 16 * sizeof(float);
  float* tsc  = (float*)p; p += SS * 16 * sizeof(float);

  {
    WDescA da;
    for (int l = 0; l < 2; ++l) {
      da.d[l * 7 + 0] = { Wq + (size_t)l * 65536, wqkvgt + (size_t)l * 262144 + 0 * 65536, 256, 256 };
      da.d[l * 7 + 1] = { Wk + (size_t)l * 65536, wqkvgt + (size_t)l * 262144 + 1 * 65536, 256, 256 };
      da.d[l * 7 + 2] = { Wv + (size_t)l * 65536, wqkvgt + (size_t)l * 262144 + 2 * 65536, 256, 256 };
      da.d[l * 7 + 3] = { Wg + (size_t)l * 65536, wqkvgt + (size_t)l * 262144 + 3 * 65536, 256, 256 };
      da.d[l * 7 + 4] = { Wo + (size_t)l * 65536, wot + (size_t)l * 65536, 256, 256 };
      da.d[l * 7 + 5] = { w1 + (size_t)l * 262144, w1t + (size_t)l * 262144, 256, 1024 };
      da.d[l * 7 + 6] = { w2 + (size_t)l * 262144, w2t + (size_t)l * 262144, 1024, 256 };
    }
    da.tsn = tsn; da.tcs = tcs; da.tsc = tsc;
    wconv_k<<<dim3(32, 32, 15), dim3(32, 8), 0, stream>>>(da);
  }

  // layer 0 LN1 (layer 1's LN1 is fused into layer 0's mega epilogue)
  ln_k<bf16><<<dim3(MM), 256, 0, stream>>>(X, ln1w, ln1b, xn);

  for (int l = 0; l < LYR; ++l) {
    mgemm_k<64, 128, DD, E_QKVG><<<dim3(MM / 64, 1024 / 128), 256, 0, stream>>>(
        xn, wqkvgt + (size_t)l * 262144, qb, kb, vT, gbuf, tsn, tcs, tsc);
    attn_k<<<dim3(BB * HH, SS / 64), 256, 0, stream>>>(qb, kb, vT, gbuf, gnw + l * DD, gnb + l * DD, ub);
    if (l == LYR - 1) {
      ffn_mega<true><<<dim3(MM / 32), 512, 0, stream>>>(
          ub, wot + (size_t)l * 65536, w1t + (size_t)l * 262144, w2t + (size_t)l * 262144,
          b1 + l * FFD, b2 + l * DD, (l == 0) ? X : yres,
          nullptr, nullptr, (float*)d_out,
          ln2w + l * DD, ln2b + l * DD, lnfw, lnfb, nullptr, nullptr);
    } else {
      ffn_mega<false><<<dim3(MM / 32), 512, 0, stream>>>(
          ub, wot + (size_t)l * 65536, w1t + (size_t)l * 262144, w2t + (size_t)l * 262144,
          b1 + l * FFD, b2 + l * DD, (l == 0) ? X : yres,
          yres, xn, nullptr,
          ln2w + l * DD, ln2b + l * DD, lnfw, lnfb, ln1w + (l + 1) * DD, ln1b + (l + 1) * DD);
    }
  }
}

// Round 17
// 178.125 us; speedup vs baseline: 1.1261x; 1.0011x over previous
//
#include <hip/hip_runtime.h>
#include <hip/hip_bf16.h>

typedef __hip_bfloat16 bf16;
typedef unsigned short ushort_t;
typedef __attribute__((ext_vector_type(8))) short short8v;
typedef __attribute__((ext_vector_type(4))) float f32x4;
typedef __attribute__((ext_vector_type(4))) unsigned int uint4v;

// RetNet block: L=2, B=4, S=2048, D=256, H=8, HD=32, FFN*D=1024
#define LYR 2
#define BB 4
#define SS 2048
#define DD 256
#define HH 8
#define HDD 32
#define FFD 1024
#define MM (BB*SS)   // 8192 tokens

__device__ __forceinline__ unsigned int cvtpk(float lo, float hi) {
  unsigned int r;
  asm("v_cvt_pk_bf16_f32 %0, %1, %2" : "=v"(r) : "v"(lo), "v"(hi));
  return r;
}
__device__ __forceinline__ ushort_t f2b1(float x) { return (ushort_t)cvtpk(x, x); }

__device__ __forceinline__ void gload_lds16(const void* g, void* l) {
  __builtin_amdgcn_global_load_lds((const __attribute__((address_space(1))) void*)g,
                                   (__attribute__((address_space(3))) void*)l, 16, 0, 0);
}

// decay exponent: l2g(h) = log2(1 - exp(log(1/32) + h*(log(1/512)-log(1/32))/7))  (negative)
__device__ __forceinline__ float l2g_of(int h) {
  return log2f(1.0f - expf(-3.4657359028f - 0.3960841187f * (float)h));
}

// ---------------- weight transpose+convert + xPos tables (z==14) ----------------
struct WDesc { const float* src; bf16* dst; int K; int N; };
struct WDescA { WDesc d[14]; float* tsn; float* tcs; float* tsc; };
__global__ __launch_bounds__(256) void wconv_k(WDescA da) {
  if (blockIdx.z == 14) {
    int i = (blockIdx.y * 32 + blockIdx.x) * 256 + threadIdx.y * 32 + threadIdx.x;
    if (i >= SS * 16) return;
    int s = i >> 4, j = i & 15;
    float sv = (2.0f * (float)j + 0.4f * (float)HDD) / (1.4f * (float)HDD);
    da.tsc[i] = powf(sv, (float)s * (1.0f / 512.0f));
    float inv_freq = powf(10000.0f, -(float)j * (1.0f / 16.0f));
    float ang = (float)s * inv_freq;
    da.tsn[i] = sinf(ang);
    da.tcs[i] = cosf(ang);
    return;
  }
  WDesc dd = da.d[blockIdx.z];
  int n0 = blockIdx.x * 32, k0 = blockIdx.y * 32;
  if (n0 >= dd.N || k0 >= dd.K) return;
  __shared__ float t[32][33];
  int tx = threadIdx.x, ty = threadIdx.y;   // 32 x 8
  #pragma unroll
  for (int i = 0; i < 32; i += 8) t[ty + i][tx] = dd.src[(size_t)(k0 + ty + i) * dd.N + n0 + tx];
  __syncthreads();
  #pragma unroll
  for (int i = 0; i < 32; i += 8) dd.dst[(size_t)(n0 + ty + i) * dd.K + k0 + tx] = __float2bfloat16(t[tx][ty + i]);
}

// ---------------- LayerNorm over D=256 (one block per row), f32 in, OT out ----------------
template<typename OT>
__global__ __launch_bounds__(256) void ln_k(const float* __restrict__ in, const float* __restrict__ w,
    const float* __restrict__ b, OT* __restrict__ out)
{
  int row = blockIdx.x, t = threadIdx.x;
  float v = in[(size_t)row * DD + t];
  __shared__ float red[4];
  float s = v;
  #pragma unroll
  for (int m = 32; m >= 1; m >>= 1) s += __shfl_xor(s, m);
  if ((t & 63) == 0) red[t >> 6] = s;
  __syncthreads();
  float mu = (red[0] + red[1] + red[2] + red[3]) * (1.0f / 256.0f);
  float d = v - mu;
  float s2 = d * d;
  #pragma unroll
  for (int m = 32; m >= 1; m >>= 1) s2 += __shfl_xor(s2, m);
  __syncthreads();
  if ((t & 63) == 0) red[t >> 6] = s2;
  __syncthreads();
  float var = (red[0] + red[1] + red[2] + red[3]) * (1.0f / 256.0f);
  float o = d * rsqrtf(var + 1e-5f) * w[t] + b[t];
  if constexpr (sizeof(OT) == 2) out[(size_t)row * DD + t] = __float2bfloat16(o);
  else                           out[(size_t)row * DD + t] = o;
}

#define STAGEG(buf, k0s) { \
    _Pragma("unroll") \
    for (int i = 0; i < BM / 32; ++i) { \
      int slot = i * 256 + tid; int row = slot >> 3, blk = slot & 7; \
      gload_lds16(Au + (size_t)(bm + row) * K + (k0s) + ((blk ^ (row & 7))) * 8, &Al[buf][slot * 8]); \
    } \
    _Pragma("unroll") \
    for (int i = 0; i < BN / 32; ++i) { \
      int slot = i * 256 + tid; int row = slot >> 3, blk = slot & 7; \
      gload_lds16(Bu + (size_t)(bn + row) * K + (k0s) + ((blk ^ (row & 7))) * 8, &Bl[buf][slot * 8]); \
    } }

// ---------------- bf16 MFMA GEMM (QKVG projection), counted-vmcnt pipeline ----------------
enum { E_QKVG = 0 };

template<int BM, int BN, int K, int EPI>
__global__ __launch_bounds__(256) void mgemm_k(const bf16* __restrict__ Ag, const bf16* __restrict__ Wt,
    void* o0, void* o1, void* o2, void* o3,
    const float* __restrict__ tsn, const float* __restrict__ tcs, const float* __restrict__ tsc)
{
  constexpr int MT = BM / 32, NT = BN / 32;
  constexpr int WMH = BM / 2, WNH = BN / 2;
  __shared__ __align__(16) ushort_t Al[2][BM * 64];
  __shared__ __align__(16) ushort_t Bl[2][BN * 64];
  const int bm = blockIdx.x * BM;
  const int bn = blockIdx.y * BN;
  const int tid = threadIdx.x;
  const int lane = tid & 63, w = tid >> 6;
  const int lg = lane >> 4, ln = lane & 15;
  const int wr = w >> 1, wc = w & 1;
  const ushort_t* Au = (const ushort_t*)Ag;
  const ushort_t* Bu = (const ushort_t*)Wt;
  f32x4 acc[MT][NT] = {};

  STAGEG(0, 0)

  int cur = 0;
  for (int k0 = 0; k0 < K; k0 += 64) {
    const bool haveNext = (k0 + 64 < K);
    if (haveNext) {
      STAGEG(cur ^ 1, k0 + 64)
      asm volatile("s_waitcnt vmcnt(6)" ::: "memory");   // my stage-t loads landed (t+1 in flight)
    } else {
      asm volatile("s_waitcnt vmcnt(0)" ::: "memory");
    }
    __builtin_amdgcn_s_barrier();                         // everyone's stage-t landed
    #pragma unroll
    for (int kh = 0; kh < 2; ++kh) {
      short8v af[MT], bfr[NT];
      #pragma unroll
      for (int mt = 0; mt < MT; ++mt) {
        int row = wr * WMH + mt * 16 + ln;
        af[mt] = *(const short8v*)&Al[cur][row * 64 + (((kh * 4 + lg) ^ (row & 7))) * 8];
      }
      #pragma unroll
      for (int nt = 0; nt < NT; ++nt) {
        int row = wc * WNH + nt * 16 + ln;
        bfr[nt] = *(const short8v*)&Bl[cur][row * 64 + (((kh * 4 + lg) ^ (row & 7))) * 8];
      }
      #pragma unroll
      for (int mt = 0; mt < MT; ++mt)
        #pragma unroll
        for (int nt = 0; nt < NT; ++nt)
          acc[mt][nt] = __builtin_amdgcn_mfma_f32_16x16x32_bf16(af[mt], bfr[nt], acc[mt][nt], 0, 0, 0);
    }
    __builtin_amdgcn_s_barrier();                         // readers done before next overwrite
    cur ^= 1;
  }

  #pragma unroll
  for (int mt = 0; mt < MT; ++mt)
    #pragma unroll
    for (int nt = 0; nt < NT; ++nt) {
      const int colbase = bn + wc * WNH + nt * 16;
      const int sec = colbase >> 8;          // 0=Q 1=K 2=V 3=G (uniform per block)
      const int c = (colbase & 255) + ln;
      const int grow0 = bm + wr * WMH + mt * 16 + lg * 4;
      if (sec <= 1) {
        const int jj = (c & 31) >> 1;
        const float l2g = l2g_of(c >> 5);
        #pragma unroll
        for (int r = 0; r < 4; ++r) {
          const int grow = grow0 + r;
          const int s = grow & (SS - 1);
          float v = acc[mt][nt][r];
          float pv = __shfl_xor(v, 1);
          float scv = tsc[s * 16 + jj];
          if (sec == 1) scv = 1.0f / scv;
          float ce = tcs[s * 16 + jj] * scv, se = tsn[s * 16 + jj] * scv;
          float o = (ln & 1) ? (v * ce + pv * se) : (v * ce - pv * se);
          if (sec == 0) o *= exp2f(l2g * (float)s);   // fold decay g^n into Q
          bf16* dst = (sec == 0) ? (bf16*)o0 : (bf16*)o1;
          dst[(size_t)grow * DD + c] = __float2bfloat16(o);
        }
      } else if (sec == 2) {
        // V transposed + fold g^(-m): vT[(b*8+h)*32 + d][s] = v(m=s,d) * g^(-s)
        const int b = grow0 >> 11, s0 = grow0 & (SS - 1);
        const int h = c >> 5, d = c & 31;
        const float nl2g = -l2g_of(h);                // positive
        float v0 = acc[mt][nt][0] * exp2f(nl2g * (float)(s0 + 0));
        float v1 = acc[mt][nt][1] * exp2f(nl2g * (float)(s0 + 1));
        float v2 = acc[mt][nt][2] * exp2f(nl2g * (float)(s0 + 2));
        float v3 = acc[mt][nt][3] * exp2f(nl2g * (float)(s0 + 3));
        uint2 pk;
        pk.x = cvtpk(v0, v1);
        pk.y = cvtpk(v2, v3);
        *(uint2*)((ushort_t*)o2 + ((size_t)(b * 8 + h) * 32 + d) * SS + s0) = pk;
      } else {
        #pragma unroll
        for (int r = 0; r < 4; ++r)
          ((float*)o3)[(size_t)(grow0 + r) * DD + c] = acc[mt][nt][r];
      }
    }
}

// ---------------- FFN mega-kernel v4: BM=32, 8 waves, depth-2 counted prefetch ----------------
template<bool LAST>
__global__ __launch_bounds__(512, 1) void ffn_mega(
    const bf16* __restrict__ ubg, const bf16* __restrict__ wotg,
    const bf16* __restrict__ w1tg, const bf16* __restrict__ w2tg,
    const float* __restrict__ b1v, const float* __restrict__ b2v,
    const float* __restrict__ resin,
    float* __restrict__ yres, bf16* __restrict__ xn, float* __restrict__ dout,
    const float* __restrict__ l2w, const float* __restrict__ l2b,
    const float* __restrict__ lfw, const float* __restrict__ lfb,
    const float* __restrict__ l1w, const float* __restrict__ l1b)
{
  __shared__ __align__(16) ushort_t Bs[8][3][2048];    // 96 KB: per-wave 32n x 64k, 3 bufs
  __shared__ __align__(16) ushort_t Xs[8192];          // 16 KB: A [32][256] swizzled (ub, then LN2)
  __shared__ __align__(16) ushort_t Us[8192];          // 16 KB: LN red scratch + GELU chunk

  const int bm = blockIdx.x * 32;
  const int tid = threadIdx.x;
  const int lane = tid & 63, w = tid >> 6;
  const int lg = lane >> 4, ln = lane & 15;
  const int row0 = lg * 4;
  const ushort_t* ubu  = (const ushort_t*)ubg;
  const ushort_t* wotu = (const ushort_t*)wotg;
  const ushort_t* w1tu = (const ushort_t*)w1tg;
  const ushort_t* w2tu = (const ushort_t*)w2tg;
  float* red = (float*)Us;   // [8 waves][32 rows][2], 2 KB

  float resv[2][2][4];
  #pragma unroll
  for (int mt = 0; mt < 2; ++mt)
    #pragma unroll
    for (int nt = 0; nt < 2; ++nt) {
      const int gcol = w * 32 + nt * 16 + ln;
      #pragma unroll
      for (int r = 0; r < 4; ++r)
        resv[mt][nt][r] = resin[(size_t)(bm + mt * 16 + row0 + r) * DD + gcol];
    }
  float b1r[4][2];
  #pragma unroll
  for (int c = 0; c < 4; ++c)
    #pragma unroll
    for (int nt = 0; nt < 2; ++nt)
      b1r[c][nt] = b1v[c * 256 + w * 32 + nt * 16 + ln];
  float b2r[2], l2wr[2], l2br[2], lfwr[2], lfbr[2], l1wr[2], l1br[2];
  #pragma unroll
  for (int nt = 0; nt < 2; ++nt) {
    const int gcol = w * 32 + nt * 16 + ln;
    b2r[nt] = b2v[gcol];
    l2wr[nt] = l2w[gcol]; l2br[nt] = l2b[gcol];
    lfwr[nt] = lfw[gcol]; lfbr[nt] = lfb[gcol];
    if constexpr (!LAST) { l1wr[nt] = l1w[gcol]; l1br[nt] = l1b[gcol]; }
  }

  #define STAGEBW(base, stride, nbase, koff, par) { \
    _Pragma("unroll") \
    for (int i = 0; i < 4; ++i) { \
      int slot = i * 64 + lane; int r = slot >> 3, blk = slot & 7; \
      gload_lds16((base) + (size_t)((nbase) + w * 32 + r) * (stride) + (koff) + ((blk ^ (r & 7))) * 8, &Bs[w][par][slot * 8]); \
    } }
  #define STAGEA { \
    _Pragma("unroll") \
    for (int i = 0; i < 2; ++i) { \
      int slot = i * 512 + tid; int row = slot >> 5, b5 = slot & 31; \
      int sb = (b5 & ~7) | ((b5 & 7) ^ (row & 7)); \
      gload_lds16(ubu + (size_t)(bm + row) * DD + sb * 8, &Xs[slot * 8]); \
    } }
  #define VMW8 asm volatile("s_waitcnt vmcnt(8)" ::: "memory");
  #define VMW4 asm volatile("s_waitcnt vmcnt(4)" ::: "memory");
  #define VMW0 asm volatile("s_waitcnt vmcnt(0)" ::: "memory");
  #define FSTEP(Aarr, s, par, accv) { \
    _Pragma("unroll") \
    for (int kh = 0; kh < 2; ++kh) { \
      short8v af[2], bfr[2]; \
      _Pragma("unroll") \
      for (int mt = 0; mt < 2; ++mt) { \
        int ra = mt * 16 + ln; \
        af[mt] = *(const short8v*)&Aarr[ra * 256 + (s) * 64 + (((kh * 4 + lg) ^ (ra & 7))) * 8]; \
      } \
      _Pragma("unroll") \
      for (int nt = 0; nt < 2; ++nt) { \
        int rb = nt * 16 + ln; \
        bfr[nt] = *(const short8v*)&Bs[w][par][rb * 64 + (((kh * 4 + lg) ^ (rb & 7))) * 8]; \
      } \
      _Pragma("unroll") \
      for (int mt = 0; mt < 2; ++mt) \
        _Pragma("unroll") \
        for (int nt = 0; nt < 2; ++nt) \
          accv[mt][nt] = __builtin_amdgcn_mfma_f32_16x16x32_bf16(af[mt], bfr[nt], accv[mt][nt], 0, 0, 0); \
    } }
  #define SWZST(buf, row, col, val) { \
    int g_ = (col) >> 3, sub_ = (col) & 7; \
    int gs_ = (g_ & ~7) | ((g_ & 7) ^ ((row) & 7)); \
    buf[(row) * 256 + gs_ * 8 + sub_] = f2b1(val); }

  STAGEA
  STAGEBW(wotu, 256, 0, 0, 0)
  STAGEBW(wotu, 256, 0, 64, 1)
  VMW4
  __builtin_amdgcn_s_barrier();

  f32x4 accw[2][2] = {};
  #pragma unroll
  for (int s = 0; s < 4; ++s) {
    if (s < 2) STAGEBW(wotu, 256, 0, (s + 2) * 64, (s + 2) % 3)
    else       STAGEBW(w1tu, 256, 0, (s - 2) * 64, (s + 2) % 3)
    VMW8
    FSTEP(Xs, s, s % 3, accw)
  }

  float v[2][2][4];
  #pragma unroll
  for (int mt = 0; mt < 2; ++mt)
    #pragma unroll
    for (int nt = 0; nt < 2; ++nt)
      #pragma unroll
      for (int r = 0; r < 4; ++r) v[mt][nt][r] = accw[mt][nt][r] + resv[mt][nt][r];
  float mu[2][4], rsg[2][4];
  {
    #pragma unroll
    for (int mt = 0; mt < 2; ++mt)
      #pragma unroll
      for (int r = 0; r < 4; ++r) {
        float s1 = 0.f, s2 = 0.f;
        #pragma unroll
        for (int nt = 0; nt < 2; ++nt) { s1 += v[mt][nt][r]; s2 += v[mt][nt][r] * v[mt][nt][r]; }
        #pragma unroll
        for (int m = 8; m >= 1; m >>= 1) { s1 += __shfl_xor(s1, m); s2 += __shfl_xor(s2, m); }
        if (ln == 0) { red[(w * 32 + mt * 16 + row0 + r) * 2] = s1; red[(w * 32 + mt * 16 + row0 + r) * 2 + 1] = s2; }
      }
    __syncthreads();
    #pragma unroll
    for (int mt = 0; mt < 2; ++mt)
      #pragma unroll
      for (int r = 0; r < 4; ++r) {
        float S = 0.f, S2 = 0.f;
        #pragma unroll
        for (int ww = 0; ww < 8; ++ww) {
          S  += red[(ww * 32 + mt * 16 + row0 + r) * 2];
          S2 += red[(ww * 32 + mt * 16 + row0 + r) * 2 + 1];
        }
        float m_ = S * (1.0f / 256.0f);
        mu[mt][r] = m_; rsg[mt][r] = rsqrtf(S2 * (1.0f / 256.0f) - m_ * m_ + 1e-5f);
      }
  }
  __syncthreads();
  #pragma unroll
  for (int mt = 0; mt < 2; ++mt)
    #pragma unroll
    for (int nt = 0; nt < 2; ++nt) {
      const int col = w * 32 + nt * 16 + ln;
      #pragma unroll
      for (int r = 0; r < 4; ++r) {
        const int row = mt * 16 + row0 + r;
        float xv = (v[mt][nt][r] - mu[mt][r]) * rsg[mt][r] * l2wr[nt] + l2br[nt];
        SWZST(Xs, row, col, xv)
      }
    }
  __syncthreads();

  f32x4 acc2[2][2] = {};
  #pragma unroll
  for (int c = 0; c < 4; ++c) {
    f32x4 acc1[2][2] = {};
    #pragma unroll
    for (int s = 0; s < 4; ++s) {
      if (s < 2) STAGEBW(w1tu, 256, c * 256, (s + 2) * 64, (6 + 8 * c + s) % 3)
      else       STAGEBW(w2tu, 1024, 0, c * 256 + (s - 2) * 64, (6 + 8 * c + s) % 3)
      VMW8
      FSTEP(Xs, s, (4 + 8 * c + s) % 3, acc1)
    }
    __syncthreads();
    #pragma unroll
    for (int mt = 0; mt < 2; ++mt)
      #pragma unroll
      for (int nt = 0; nt < 2; ++nt) {
        const int col = w * 32 + nt * 16 + ln;
        #pragma unroll
        for (int r = 0; r < 4; ++r) {
          const int row = mt * 16 + row0 + r;
          float t = acc1[mt][nt][r] + b1r[c][nt];
          t = 0.5f * t * (1.0f + erff(t * 0.70710678118654752f));
          SWZST(Us, row, col, t)
        }
      }
    __syncthreads();
    #pragma unroll
    for (int s = 0; s < 4; ++s) {
      if (s < 2)      STAGEBW(w2tu, 1024, 0, c * 256 + (s + 2) * 64, (10 + 8 * c + s) % 3)
      else if (c < 3) STAGEBW(w1tu, 256, (c + 1) * 256, (s - 2) * 64, (10 + 8 * c + s) % 3)
      if (c == 3 && s == 2) { VMW4 }
      else if (c == 3 && s == 3) { VMW0 }
      else { VMW8 }
      FSTEP(Us, s, (8 + 8 * c + s) % 3, acc2)
    }
  }
  __syncthreads();

  float f[2][2][4];
  #pragma unroll
  for (int mt = 0; mt < 2; ++mt)
    #pragma unroll
    for (int nt = 0; nt < 2; ++nt)
      #pragma unroll
      for (int r = 0; r < 4; ++r)
        f[mt][nt][r] = acc2[mt][nt][r] + b2r[nt] + v[mt][nt][r];
  {
    #pragma unroll
    for (int mt = 0; mt < 2; ++mt)
      #pragma unroll
      for (int r = 0; r < 4; ++r) {
        float s1 = 0.f, s2 = 0.f;
        #pragma unroll
        for (int nt = 0; nt < 2; ++nt) { s1 += f[mt][nt][r]; s2 += f[mt][nt][r] * f[mt][nt][r]; }
        #pragma unroll
        for (int m = 8; m >= 1; m >>= 1) { s1 += __shfl_xor(s1, m); s2 += __shfl_xor(s2, m); }
        if (ln == 0) { red[(w * 32 + mt * 16 + row0 + r) * 2] = s1; red[(w * 32 + mt * 16 + row0 + r) * 2 + 1] = s2; }
      }
    __syncthreads();
    #pragma unroll
    for (int mt = 0; mt < 2; ++mt)
      #pragma unroll
      for (int r = 0; r < 4; ++r) {
        float S = 0.f, S2 = 0.f;
        #pragma unroll
        for (int ww = 0; ww < 8; ++ww) {
          S  += red[(ww * 32 + mt * 16 + row0 + r) * 2];
          S2 += red[(ww * 32 + mt * 16 + row0 + r) * 2 + 1];
        }
        float m_ = S * (1.0f / 256.0f);
        mu[mt][r] = m_; rsg[mt][r] = rsqrtf(S2 * (1.0f / 256.0f) - m_ * m_ + 1e-5f);
      }
  }
  float u[2][2][4];
  #pragma unroll
  for (int mt = 0; mt < 2; ++mt)
    #pragma unroll
    for (int nt = 0; nt < 2; ++nt)
      #pragma unroll
      for (int r = 0; r < 4; ++r)
        u[mt][nt][r] = (f[mt][nt][r] - mu[mt][r]) * rsg[mt][r] * lfwr[nt] + lfbr[nt];
  if constexpr (LAST) {
    #pragma unroll
    for (int mt = 0; mt < 2; ++mt)
      #pragma unroll
      for (int nt = 0; nt < 2; ++nt) {
        const int gcol = w * 32 + nt * 16 + ln;
        #pragma unroll
        for (int r = 0; r < 4; ++r)
          dout[(size_t)(bm + mt * 16 + row0 + r) * DD + gcol] = u[mt][nt][r];
      }
  } else {
    __syncthreads();
    #pragma unroll
    for (int mt = 0; mt < 2; ++mt)
      #pragma unroll
      for (int r = 0; r < 4; ++r) {
        float s1 = 0.f, s2 = 0.f;
        #pragma unroll
        for (int nt = 0; nt < 2; ++nt) { s1 += u[mt][nt][r]; s2 += u[mt][nt][r] * u[mt][nt][r]; }
        #pragma unroll
        for (int m = 8; m >= 1; m >>= 1) { s1 += __shfl_xor(s1, m); s2 += __shfl_xor(s2, m); }
        if (ln == 0) { red[(w * 32 + mt * 16 + row0 + r) * 2] = s1; red[(w * 32 + mt * 16 + row0 + r) * 2 + 1] = s2; }
      }
    __syncthreads();
    float mu2[2][4], rs2[2][4];
    #pragma unroll
    for (int mt = 0; mt < 2; ++mt)
      #pragma unroll
      for (int r = 0; r < 4; ++r) {
        float S = 0.f, S2 = 0.f;
        #pragma unroll
        for (int ww = 0; ww < 8; ++ww) {
          S  += red[(ww * 32 + mt * 16 + row0 + r) * 2];
          S2 += red[(ww * 32 + mt * 16 + row0 + r) * 2 + 1];
        }
        float m_ = S * (1.0f / 256.0f);
        mu2[mt][r] = m_; rs2[mt][r] = rsqrtf(S2 * (1.0f / 256.0f) - m_ * m_ + 1e-5f);
      }
    #pragma unroll
    for (int mt = 0; mt < 2; ++mt)
      #pragma unroll
      for (int nt = 0; nt < 2; ++nt) {
        const int gcol = w * 32 + nt * 16 + ln;
        #pragma unroll
        for (int r = 0; r < 4; ++r) {
          const size_t idx = (size_t)(bm + mt * 16 + row0 + r) * DD + gcol;
          yres[idx] = u[mt][nt][r];
          xn[idx] = __float2bfloat16((u[mt][nt][r] - mu2[mt][r]) * rs2[mt][r] * l1wr[nt] + l1br[nt]);
        }
      }
  }
  #undef STAGEBW
  #undef STAGEA
  #undef VMW8
  #undef VMW4
  #undef VMW0
  #undef FSTEP
  #undef SWZST
}

// ---------------- Retention + fused GroupNorm/SiLU-gate, counted-vmcnt pipeline ----------------
// Decay pre-folded: q *= g^n, vT *= g^(-m). Inner loop: raw QK -> pack -> PV.
__global__ __launch_bounds__(256) void attn_k(const bf16* __restrict__ qg, const bf16* __restrict__ kg,
    const bf16* __restrict__ vtg, const float* __restrict__ gbuf,
    const float* __restrict__ gnw, const float* __restrict__ gnb, bf16* __restrict__ ub)
{
  __shared__ __align__(16) ushort_t Kl[2][64 * 32];      // [m][k], blk ^= m&3
  __shared__ __align__(16) ushort_t Vl[2][32 * 64];      // [d][m], blk ^= d&7
  __shared__ __align__(16) unsigned int Pl[4][512];      // per wave: P^T[n=ln][64 m] bf16

  const int bh = blockIdx.x;
  const int b = bh >> 3, h = bh & (HH - 1);
  const int n0 = ((int)gridDim.y - 1 - (int)blockIdx.y) * 64;
  const int tid = threadIdx.x;
  const int w = tid >> 6, lane = tid & 63;
  const int lg = lane >> 4, ln = lane & 15;

  const size_t base = (size_t)b * SS * DD + h * HDD;
  const ushort_t* qp = (const ushort_t*)qg + base;
  const ushort_t* kp = (const ushort_t*)kg + base;
  const ushort_t* vtp = (const ushort_t*)vtg + (size_t)(b * 8 + h) * 32 * SS;

  const int n = n0 + w * 16 + ln;
  const short8v qf = *(const short8v*)(qp + (size_t)n * DD + lg * 8);

  const float l2g = l2g_of(h);                     // negative; only for window calc
  f32x4 acc0 = {0,0,0,0}, acc1 = {0,0,0,0};

  const int Wwin = (int)(20.0f / (-l2g)) + 1;
  int m_lo = 0;
  if (n0 > Wwin) m_lo = ((n0 - Wwin) >> 6) << 6;

  const int Krow = tid >> 2, Kc8 = tid & 3;
  const int Vrow = tid >> 3, Vc8 = tid & 7;

  #define STAGE(buf, m0s) { \
    gload_lds16(kp + (size_t)((m0s) + Krow) * DD + ((Kc8 ^ (Krow & 3)) * 8), &Kl[buf][tid * 8]); \
    gload_lds16(vtp + (size_t)Vrow * SS + (m0s) + ((Vc8 ^ (Vrow & 7)) * 8), &Vl[buf][tid * 8]); }

  STAGE(0, m_lo)

  int cur = 0;
  for (int m0 = m_lo; m0 <= n0; m0 += 64) {
    if (m0 < n0) {
      STAGE(cur ^ 1, m0 + 64)
      asm volatile("s_waitcnt vmcnt(2)" ::: "memory");   // my tile-t loads landed (t+1 in flight)
    } else {
      asm volatile("s_waitcnt vmcnt(0)" ::: "memory");
    }
    __builtin_amdgcn_s_barrier();                         // everyone's tile-t landed
    const bool diag = (m0 == n0);
    __builtin_amdgcn_s_setprio(1);
    #pragma unroll
    for (int mt = 0; mt < 4; ++mt) {
      const int krow = mt * 16 + ln;
      short8v kf = *(const short8v*)&Kl[cur][krow * 32 + ((lg ^ (krow & 3)) << 3)];
      f32x4 z = {0,0,0,0};
      f32x4 pa = __builtin_amdgcn_mfma_f32_16x16x32_bf16(kf, qf, z, 0, 0, 0);
      float v0 = pa[0], v1 = pa[1], v2 = pa[2], v3 = pa[3];
      if (diag) {
        const int m = n0 + mt * 16 + lg * 4;
        v0 = (n < m)     ? 0.f : v0;
        v1 = (n < m + 1) ? 0.f : v1;
        v2 = (n < m + 2) ? 0.f : v2;
        v3 = (n < m + 3) ? 0.f : v3;
      }
      uint2 pk;
      pk.x = cvtpk(v0, v1);
      pk.y = cvtpk(v2, v3);
      const int blk = (mt * 2 + (lg >> 1)) ^ (ln & 7);
      *(uint2*)&Pl[w][ln * 32 + blk * 4 + (lg & 1) * 2] = pk;
    }
    #pragma unroll
    for (int hh = 0; hh < 2; ++hh) {
      const int pblk = (hh * 4 + lg) ^ (ln & 7);
      uint4v pw = *(const uint4v*)&Pl[w][ln * 32 + pblk * 4];
      short8v pf = __builtin_bit_cast(short8v, pw);
      #pragma unroll
      for (int dt = 0; dt < 2; ++dt) {
        const int d = dt * 16 + ln;
        short8v vf = *(const short8v*)&Vl[cur][d * 64 + (((hh * 4 + lg) ^ (d & 7)) << 3)];
        if (dt == 0) acc0 = __builtin_amdgcn_mfma_f32_16x16x32_bf16(vf, pf, acc0, 0, 0, 0);
        else         acc1 = __builtin_amdgcn_mfma_f32_16x16x32_bf16(vf, pf, acc1, 0, 0, 0);
      }
    }
    __builtin_amdgcn_s_setprio(0);
    __builtin_amdgcn_s_barrier();                         // readers done before next overwrite
    cur ^= 1;
  }
  #undef STAGE

  // ---- fused GroupNorm (per head) + SiLU gate ----
  float gwv[8], gbv[8];
  #pragma unroll
  for (int dt = 0; dt < 2; ++dt) {
    f32x4 a = *(const f32x4*)&gnw[h * 32 + dt * 16 + lg * 4];
    f32x4 c = *(const f32x4*)&gnb[h * 32 + dt * 16 + lg * 4];
    #pragma unroll
    for (int r = 0; r < 4; ++r) { gwv[dt * 4 + r] = a[r]; gbv[dt * 4 + r] = c[r]; }
  }
  float s = 0.f;
  #pragma unroll
  for (int r = 0; r < 4; ++r) s += acc0[r] + acc1[r];
  s += __shfl_xor(s, 16); s += __shfl_xor(s, 32);
  const float mu = s * (1.0f / 32.0f);
  float s2 = 0.f;
  #pragma unroll
  for (int r = 0; r < 4; ++r) { float d0 = acc0[r] - mu, d1 = acc1[r] - mu; s2 += d0 * d0 + d1 * d1; }
  s2 += __shfl_xor(s2, 16); s2 += __shfl_xor(s2, 32);
  const float rs = rsqrtf(s2 * (1.0f / 32.0f) + 1e-5f);
  const size_t rowoff = ((size_t)b * SS + n) * DD + h * 32;
  #pragma unroll
  for (int dt = 0; dt < 2; ++dt) {
    f32x4 yv = dt ? acc1 : acc0;
    f32x4 gv = *(const f32x4*)&gbuf[rowoff + dt * 16 + lg * 4];
    float o0, o1, o2, o3;
    {
      float yn0 = (yv[0] - mu) * rs * gwv[dt * 4 + 0] + gbv[dt * 4 + 0];
      float yn1 = (yv[1] - mu) * rs * gwv[dt * 4 + 1] + gbv[dt * 4 + 1];
      float yn2 = (yv[2] - mu) * rs * gwv[dt * 4 + 2] + gbv[dt * 4 + 2];
      float yn3 = (yv[3] - mu) * rs * gwv[dt * 4 + 3] + gbv[dt * 4 + 3];
      o0 = gv[0] / (1.0f + expf(-gv[0])) * yn0;
      o1 = gv[1] / (1.0f + expf(-gv[1])) * yn1;
      o2 = gv[2] / (1.0f + expf(-gv[2])) * yn2;
      o3 = gv[3] / (1.0f + expf(-gv[3])) * yn3;
    }
    uint2 pk;
    pk.x = cvtpk(o0, o1);
    pk.y = cvtpk(o2, o3);
    *(uint2*)((ushort_t*)ub + rowoff + dt * 16 + lg * 4) = pk;
  }
}

extern "C" void kernel_launch(void* const* d_in, const int* in_sizes, int n_in,
                              void* d_out, int out_size, void* d_ws, size_t ws_size,
                              hipStream_t stream)
{
  const float* X    = (const float*)d_in[0];
  const float* Wq   = (const float*)d_in[1];
  const float* Wk   = (const float*)d_in[2];
  const float* Wv   = (const float*)d_in[3];
  const float* Wg   = (const float*)d_in[4];
  const float* Wo   = (const float*)d_in[5];
  const float* gnw  = (const float*)d_in[6];
  const float* gnb  = (const float*)d_in[7];
  const float* ln1w = (const float*)d_in[8];
  const float* ln1b = (const float*)d_in[9];
  const float* ln2w = (const float*)d_in[10];
  const float* ln2b = (const float*)d_in[11];
  const float* w1   = (const float*)d_in[12];
  const float* b1   = (const float*)d_in[13];
  const float* w2   = (const float*)d_in[14];
  const float* b2   = (const float*)d_in[15];
  const float* lnfw = (const float*)d_in[16];
  const float* lnfb = (const float*)d_in[17];

  // Workspace (~40 MiB)
  char* p = (char*)d_ws;
  const size_t AF  = (size_t)MM * DD * sizeof(float);  // 8 MiB
  const size_t ABF = (size_t)MM * DD * sizeof(bf16);   // 4 MiB
  bf16*  xn   = (bf16*)p;  p += ABF;
  bf16*  qb   = (bf16*)p;  p += ABF;
  bf16*  kb   = (bf16*)p;  p += ABF;
  bf16*  vT   = (bf16*)p;  p += ABF;   // [B][H][32][S], pre-scaled by g^(-m)
  bf16*  ub   = (bf16*)p;  p += ABF;
  float* gbuf = (float*)p; p += AF;
  float* yres = (float*)p; p += AF;
  bf16*  wqkvgt = (bf16*)p; p += (size_t)2 * 1024 * 256 * sizeof(bf16);
  bf16*  wot    = (bf16*)p; p += (size_t)2 * 256 * 256 * sizeof(bf16);
  bf16*  w1t    = (bf16*)p; p += (size_t)2 * 1024 * 256 * sizeof(bf16);
  bf16*  w2t    = (bf16*)p; p += (size_t)2 * 256 * 1024 * sizeof(bf16);
  float* tsn  = (float*)p; p += SS * 16 * sizeof(float);
  float* tcs  = (float*)p; p += SS * 16 * sizeof(float);
  float* tsc  = (float*)p; p += SS * 16 * sizeof(float);

  {
    WDescA da;
    for (int l = 0; l < 2; ++l) {
      da.d[l * 7 + 0] = { Wq + (size_t)l * 65536, wqkvgt + (size_t)l * 262144 + 0 * 65536, 256, 256 };
      da.d[l * 7 + 1] = { Wk + (size_t)l * 65536, wqkvgt + (size_t)l * 262144 + 1 * 65536, 256, 256 };
      da.d[l * 7 + 2] = { Wv + (size_t)l * 65536, wqkvgt + (size_t)l * 262144 + 2 * 65536, 256, 256 };
      da.d[l * 7 + 3] = { Wg + (size_t)l * 65536, wqkvgt + (size_t)l * 262144 + 3 * 65536, 256, 256 };
      da.d[l * 7 + 4] = { Wo + (size_t)l * 65536, wot + (size_t)l * 65536, 256, 256 };
      da.d[l * 7 + 5] = { w1 + (size_t)l * 262144, w1t + (size_t)l * 262144, 256, 1024 };
      da.d[l * 7 + 6] = { w2 + (size_t)l * 262144, w2t + (size_t)l * 262144, 1024, 256 };
    }
    da.tsn = tsn; da.tcs = tcs; da.tsc = tsc;
    wconv_k<<<dim3(32, 32, 15), dim3(32, 8), 0, stream>>>(da);
  }

  // layer 0 LN1 (layer 1's LN1 is fused into layer 0's mega epilogue)
  ln_k<bf16><<<dim3(MM), 256, 0, stream>>>(X, ln1w, ln1b, xn);

  for (int l = 0; l < LYR; ++l) {
    mgemm_k<64, 128, DD, E_QKVG><<<dim3(MM / 64, 1024 / 128), 256, 0, stream>>>(
        xn, wqkvgt + (size_t)l * 262144, qb, kb, vT, gbuf, tsn, tcs, tsc);
    attn_k<<<dim3(BB * HH, SS / 64), 256, 0, stream>>>(qb, kb, vT, gbuf, gnw + l * DD, gnb + l * DD, ub);
    if (l == LYR - 1) {
      ffn_mega<true><<<dim3(MM / 32), 512, 0, stream>>>(
          ub, wot + (size_t)l * 65536, w1t + (size_t)l * 262144, w2t + (size_t)l * 262144,
          b1 + l * FFD, b2 + l * DD, (l == 0) ? X : yres,
          nullptr, nullptr, (float*)d_out,
          ln2w + l * DD, ln2b + l * DD, lnfw, lnfb, nullptr, nullptr);
    } else {
      ffn_mega<false><<<dim3(MM / 32), 512, 0, stream>>>(
          ub, wot + (size_t)l * 65536, w1t + (size_t)l * 262144, w2t + (size_t)l * 262144,
          b1 + l * FFD, b2 + l * DD, (l == 0) ? X : yres,
          yres, xn, nullptr,
          ln2w + l * DD, ln2b + l * DD, lnfw, lnfb, ln1w + (l + 1) * DD, ln1b + (l + 1) * DD);
    }
  }
}